// Round 7
// baseline (197.075 us; speedup 1.0000x reference)
//
#include <hip/hip_runtime.h>
#include <cstdint>
#include <cstddef>

// ---------------------------------------------------------------------------
// ThalamicRNN step. FP32 in/out; internal GEMM bf16 MFMA + fp32 accum.
//   A'  = [ r | stim ]           (2048 x 2176) bf16   (KA = 2176 = 17*128)
//   B'  = [ J^T | I_stim^T | U ] (2048 x 2240) bf16   (KB = 2240)
//   t[b,p] = tha[b,p] * (r @ V^T)[b,p]  -- split-K partials in prep,
//            reduced per-block inside main_gemm as the final K-tile vs U.
//   acc = A'@B'^T (+ t@U^T); x_new = x + (DT/TAU)*(-x+acc+B+SIG*eps);
//   r_new = softplus(x_new)
// Round 12: BK=128. R1/R6 proved staged-byte volume is not binding (bigger
// tiles = more bytes saved = slower) and R0 vs R3 proved the data-latency
// drain is only ~1.6 us total -- the cost is the per-iteration fixed event
// overhead (2 barrier convergences + pipeline refill) x 34. Halve it:
// 17 K-iters of BK=128 at the SAME 64x64 tile / 256 threads / 4 waves /
// 4 blocks per CU (As+Bs = 32 KB single-buffered, occupancy unchanged --
// avoids m132's BK=128 failure mode which came from 64 KB LDS).
// Simple twice-verified __syncthreads staging (dbuf/vmcnt dropped: R3
// showed it buys ~nothing). 16-chunk XOR swizzle (lc = (ci&15)^(row&15),
// read XOR l15). Peeled t/U tile keeps the old 8-chunk flat-64 layout.
// XCD swizzle 16m x 8n, n-inner. prep unchanged (verified R4/R6).
// ---------------------------------------------------------------------------

#define KA 2176
#define KB 2240
#define NN 2048

using frag_ab = __attribute__((ext_vector_type(8))) short;   // 8 bf16
using frag_cd = __attribute__((ext_vector_type(4))) float;   // 4 fp32

__device__ __forceinline__ unsigned short f2bf(float f) {
  union { float f; unsigned int i; } v;
  v.f = f;
  unsigned int r = v.i + 0x7fffu + ((v.i >> 16) & 1u);  // RNE
  return (unsigned short)(r >> 16);
}

__device__ __forceinline__ uint4 cvt8(const float* __restrict__ p) {
  float4 a = *(const float4*)p;
  float4 b = *(const float4*)(p + 4);
  union { uint4 v; unsigned short u[8]; } d;
  d.u[0] = f2bf(a.x); d.u[1] = f2bf(a.y); d.u[2] = f2bf(a.z); d.u[3] = f2bf(a.w);
  d.u[4] = f2bf(b.x); d.u[5] = f2bf(b.y); d.u[6] = f2bf(b.z); d.u[7] = f2bf(b.w);
  return d.v;
}

// async global->LDS, 16 B/lane; LDS dest = wave-uniform base + lane*16.
__device__ __forceinline__ void gl_lds16(const void* g, void* l) {
  __builtin_amdgcn_global_load_lds(
      (const __attribute__((address_space(1))) void*)g,
      (__attribute__((address_space(3))) void*)l, 16, 0, 0);
}

// ---------------------------------------------------------------------------
// prep: blocks [0,1024)     J transpose -> Bp cols [0,2048)
//       [1024,1088)         I_stim transpose -> Bp cols [2048,2176)
//       [1088,1216)         stim -> Ap cols [2048,2176)   (128 blocks)
//       [1216,1280)         U -> Bp cols [2176,2240)      (64 blocks)
//       [1280,1536)         t split-K partials part[s][b][p] fp32,
//                           FUSED with r -> Ap cols [0,2048) bf16 pack
// ---------------------------------------------------------------------------
__global__ __launch_bounds__(256) void prep(
    const float* __restrict__ J, const float* __restrict__ Ist,
    const float* __restrict__ rg, const float* __restrict__ stim,
    const float* __restrict__ U, const float* __restrict__ V,
    unsigned short* __restrict__ Ap, unsigned short* __restrict__ Bp,
    float* __restrict__ part) {
  __shared__ unsigned short tile[64 * 66];
  __shared__ alignas(16) unsigned short Ats[32 * 64];
  __shared__ alignas(16) unsigned short Bts[64 * 64];
  const int blk = blockIdx.x;
  const int t = threadIdx.x;

  if (blk < 1088) {                      // ---- transposes ----
    const float* src;
    int dst_off, cx, cy;
    if (blk < 1024) { src = J;   dst_off = 0;    cx = blk & 31; cy = blk >> 5; }
    else            { src = Ist; dst_off = 2048; cx = (blk - 1024) & 31; cy = (blk - 1024) >> 5; }
    const int r0 = cy * 64, c0 = cx * 64;
    const int sr = t >> 3, c8 = t & 7;
#pragma unroll
    for (int p = 0; p < 2; ++p) {
      const int row = sr + 32 * p;
      union { uint4 v; unsigned short u[8]; } d;
      d.v = cvt8(&src[(size_t)(r0 + row) * 2048 + c0 + c8 * 8]);
#pragma unroll
      for (int e = 0; e < 8; ++e) tile[row * 66 + c8 * 8 + e] = d.u[e];
    }
    __syncthreads();
#pragma unroll
    for (int p = 0; p < 2; ++p) {
      const int scol = sr + 32 * p;
      union { uint4 v; unsigned short u[8]; } d;
#pragma unroll
      for (int e = 0; e < 8; ++e) d.u[e] = tile[(c8 * 8 + e) * 66 + scol];
      *(uint4*)&Bp[(size_t)(c0 + scol) * KB + dst_off + r0 + c8 * 8] = d.v;
    }
  } else if (blk < 1216) {               // ---- stim -> Ap[2048:2176) ----
    const int row = (blk - 1088) * 16 + (t >> 4);   // 16 rows/block
    const int ch  = t & 15;                         // 16 chunks of 8 floats
    *(uint4*)&Ap[(size_t)row * KA + 2048 + ch * 8] =
        cvt8(&stim[(size_t)row * 128 + ch * 8]);
  } else if (blk < 1280) {               // ---- U -> Bp[2176:2240) ----
    const int row = (blk - 1216) * 32 + (t >> 3);   // 32 rows/block
    const int ch  = t & 7;                          // 8 chunks of 8 floats
    *(uint4*)&Bp[(size_t)row * KB + 2176 + ch * 8] =
        cvt8(&U[(size_t)row * 64 + ch * 8]);
  } else {                               // ---- t split-K partials + r-pack ----
    const int tb = blk - 1280;
    const int mt = tb & 63, s = tb >> 6;
    const int b0 = mt * 32;
    const int wave = t >> 6, lane = t & 63;
    const int q = lane >> 4, l15 = lane & 15;
    const int arow = t >> 3, ac8 = t & 7;

    const float* gA  = rg + (size_t)(b0 + arow) * 2048 + s * 512 + ac8 * 8;
    const float* gB0 = V  + (size_t)arow        * 2048 + s * 512 + ac8 * 8;
    const float* gB1 = V  + (size_t)(arow + 32) * 2048 + s * 512 + ac8 * 8;
    // fused r->Ap pack destination (same elements this block converts)
    unsigned short* pAp = Ap + (size_t)(b0 + arow) * KA + s * 512 + ac8 * 8;

    frag_cd acc0 = {0.f, 0.f, 0.f, 0.f};
    frag_cd acc1 = {0.f, 0.f, 0.f, 0.f};

    for (int kt = 0; kt < 8; ++kt) {
      const int k0 = kt * 64;
      uint4 va  = cvt8(gA + k0);
      uint4 vb0 = cvt8(gB0 + k0);
      uint4 vb1 = cvt8(gB1 + k0);
      *(uint4*)&pAp[k0] = va;          // by-product: Ap bf16 pack
      __syncthreads();
      *(uint4*)&Ats[t * 8]        = va;
      *(uint4*)&Bts[t * 8]        = vb0;
      *(uint4*)&Bts[2048 + t * 8] = vb1;
      __syncthreads();
#pragma unroll
      for (int ks = 0; ks < 2; ++ks) {
        frag_ab a0 = *(const frag_ab*)&Ats[(l15)      * 64 + ks * 32 + q * 8];
        frag_ab a1 = *(const frag_ab*)&Ats[(16 + l15) * 64 + ks * 32 + q * 8];
        frag_ab b  = *(const frag_ab*)&Bts[(wave * 16 + l15) * 64 + ks * 32 + q * 8];
        acc0 = __builtin_amdgcn_mfma_f32_16x16x32_bf16(a0, b, acc0, 0, 0, 0);
        acc1 = __builtin_amdgcn_mfma_f32_16x16x32_bf16(a1, b, acc1, 0, 0, 0);
      }
    }
    const int p = wave * 16 + l15;
#pragma unroll
    for (int reg = 0; reg < 4; ++reg) {
      const int m0 = q * 4 + reg;   // C/D: row = quad*4+reg, col = lane&15
      part[((size_t)s * 2048 + b0 + m0) * 64 + p]      = acc0[reg];
      part[((size_t)s * 2048 + b0 + m0 + 16) * 64 + p] = acc1[reg];
    }
  }
}

// ---------------------------------------------------------------------------
// Main GEMM + fused t-reduce + epilogue. 64x64 tile, BK=128, 256 threads
// (4 waves, each 32x32, acc[2][2]). Single-buffered (As+Bs = 32 KB),
// 17 K-iters: sync -> 8x global_load_lds (4A+4B) -> sync -> 4 ks x 4 MFMA.
// Peeled 18th tile: t (from regs) vs U, 8-chunk flat-64 layout.
// XCD swizzle: each XCD owns 16(m) x 8(n) tiles, n-inner. 4 blocks/CU.
// ---------------------------------------------------------------------------
__global__ __launch_bounds__(256, 4) void main_gemm(
    const unsigned short* __restrict__ Ap, const unsigned short* __restrict__ Bp,
    const float* __restrict__ part, const float* __restrict__ tha,
    const float* __restrict__ xg, const float* __restrict__ epsg,
    const float* __restrict__ Bvec,
    float* __restrict__ outx, float* __restrict__ outr) {
  __shared__ alignas(16) unsigned short As[64 * 128];   // 16 KB
  __shared__ alignas(16) unsigned short Bs[64 * 128];   // 16 KB

  const int t = threadIdx.x;
  const int wave = t >> 6, lane = t & 63;
  const int q = lane >> 4, l15 = lane & 15, l7 = lane & 7;
  const int wm = (wave & 1) * 32, wn = (wave >> 1) * 32;

  // XCD swizzle: 1024 blocks, 8 XCDs, each owns 16(m) x 8(n) tiles, n-inner.
  const int bid = blockIdx.x;
  const int xcd = bid & 7, idx = bid >> 3;                 // idx 0..127
  const int mt = ((xcd >> 2) << 4) + (idx >> 3);           // 0..31
  const int nt = ((xcd & 3) << 3) + (idx & 7);             // 0..31
  const int bm0 = mt * 64, bn0 = nt * 64;

  // ---- A/B staging: 4 slots each, 16-chunk XOR swizzle -------------------
  // slot ci holds row=ci>>4, logical chunk (ci&15)^(row&15); LDS linear.
  const unsigned short* gA[4];
  const unsigned short* gB[4];
#pragma unroll
  for (int r = 0; r < 4; ++r) {
    const int ci = r * 256 + t;
    const int row = ci >> 4;                 // 0..63
    const int lc = (ci & 15) ^ (row & 15);
    gA[r] = Ap + (size_t)(bm0 + row) * KA + lc * 8;
    gB[r] = Bp + (size_t)(bn0 + row) * KB + lc * 8;
  }

  // ---- peeled-tile prep: t-reduce (2 slots, 8-chunk swizzle) + U ptrs ----
  uint4 tval[2];
  const unsigned short* gU[2];
#pragma unroll
  for (int r = 0; r < 2; ++r) {
    const int ci = r * 256 + t;
    const int row = ci >> 3;                 // 0..63
    const int lc = (ci & 7) ^ (row & 7);
    gU[r] = Bp + (size_t)(bn0 + row) * KB + 2176 + lc * 8;

    // t[bm0+row][p0..p0+8) = tha * sum_s part[s]
    const int p0 = lc * 8;
    const size_t base = ((size_t)(bm0 + row)) * 64 + p0;
    float4 s0 = *(const float4*)&part[base];
    float4 s1 = *(const float4*)&part[base + 4];
#pragma unroll
    for (int s = 1; s < 4; ++s) {
      float4 a = *(const float4*)&part[(size_t)s * 131072 + base];
      float4 b = *(const float4*)&part[(size_t)s * 131072 + base + 4];
      s0.x += a.x; s0.y += a.y; s0.z += a.z; s0.w += a.w;
      s1.x += b.x; s1.y += b.y; s1.z += b.z; s1.w += b.w;
    }
    float4 th0 = *(const float4*)&tha[base];
    float4 th1 = *(const float4*)&tha[base + 4];
    union { uint4 v; unsigned short u[8]; } d;
    d.u[0] = f2bf(th0.x * s0.x); d.u[1] = f2bf(th0.y * s0.y);
    d.u[2] = f2bf(th0.z * s0.z); d.u[3] = f2bf(th0.w * s0.w);
    d.u[4] = f2bf(th1.x * s1.x); d.u[5] = f2bf(th1.y * s1.y);
    d.u[6] = f2bf(th1.z * s1.z); d.u[7] = f2bf(th1.w * s1.w);
    tval[r] = d.v;
  }

  frag_cd acc[2][2];
#pragma unroll
  for (int i = 0; i < 2; ++i)
#pragma unroll
    for (int j = 0; j < 2; ++j) {
      frag_cd z = {0.f, 0.f, 0.f, 0.f};
      acc[i][j] = z;
    }

#pragma unroll 1
  for (int kt = 0; kt < 17; ++kt) {   // 17 * 128 = 2176 = KA exactly
    const int k0 = kt * 128;
    __syncthreads();                  // all waves done reading previous tile
#pragma unroll
    for (int r = 0; r < 4; ++r) {
      gl_lds16(gA[r] + k0, &As[(size_t)(r * 256 + wave * 64) * 8]);
      gl_lds16(gB[r] + k0, &Bs[(size_t)(r * 256 + wave * 64) * 8]);
    }
    __syncthreads();                  // compiler drains vmcnt before barrier
#pragma unroll
    for (int ks = 0; ks < 4; ++ks) {
      frag_ab af[2], bfr[2];
#pragma unroll
      for (int i = 0; i < 2; ++i) {
        // row stride 128 shorts; chunk = (ks*4+q) ^ (row&15), row&15 == l15
        af[i]  = *(const frag_ab*)&As[(wm + i * 16 + l15) * 128 + (((ks * 4 + q) ^ l15) * 8)];
        bfr[i] = *(const frag_ab*)&Bs[(wn + i * 16 + l15) * 128 + (((ks * 4 + q) ^ l15) * 8)];
      }
#pragma unroll
      for (int i = 0; i < 2; ++i)
#pragma unroll
        for (int j = 0; j < 2; ++j)
          acc[i][j] = __builtin_amdgcn_mfma_f32_16x16x32_bf16(af[i], bfr[j], acc[i][j], 0, 0, 0);
    }
  }

  // ---- peeled K-tile: A-side = t (from regs), B-side = U ------------------
  // flat [64][64] layout (row stride 64 shorts), 8-chunk XOR swizzle.
  {
    __syncthreads();
#pragma unroll
    for (int r = 0; r < 2; ++r) {
      *(uint4*)&As[(size_t)(r * 256 + t) * 8] = tval[r];
      gl_lds16(gU[r], &Bs[(size_t)(r * 256 + wave * 64) * 8]);
    }
    __syncthreads();
#pragma unroll
    for (int ks = 0; ks < 2; ++ks) {
      frag_ab af[2], bfr[2];
#pragma unroll
      for (int i = 0; i < 2; ++i) {
        // chunk = (ks*4+q) ^ (row&7), row&7 == l7
        af[i]  = *(const frag_ab*)&As[(wm + i * 16 + l15) * 64 + (((ks * 4 + q) ^ l7) * 8)];
        bfr[i] = *(const frag_ab*)&Bs[(wn + i * 16 + l15) * 64 + (((ks * 4 + q) ^ l7) * 8)];
      }
#pragma unroll
      for (int i = 0; i < 2; ++i)
#pragma unroll
        for (int j = 0; j < 2; ++j)
          acc[i][j] = __builtin_amdgcn_mfma_f32_16x16x32_bf16(af[i], bfr[j], acc[i][j], 0, 0, 0);
    }
  }

  // ---- epilogue: fp32 direct from accumulator C-layout -------------------
  const float A_DT = 0.33333334f;          // DT/TAU
  const float SIG  = 0.81649658092772615f; // sqrt(2*DT/TAU)
#pragma unroll
  for (int j = 0; j < 2; ++j) {
    const int nc = bn0 + wn + j * 16 + l15;    // C/D col = lane&15
    const float bvf = Bvec[nc];
#pragma unroll
    for (int i = 0; i < 2; ++i) {
#pragma unroll
      for (int reg = 0; reg < 4; ++reg) {
        const int mr = bm0 + wm + i * 16 + q * 4 + reg;  // C/D row = quad*4+reg
        const size_t off = (size_t)mr * NN + nc;
        const float xf = xg[off];
        const float ef = epsg[off];
        const float xn = xf + A_DT * (acc[i][j][reg] + bvf - xf + SIG * ef);
        outx[off] = xn;
        outr[off] = (xn > 20.f) ? xn : log1pf(__expf(xn));
      }
    }
  }
}

// ---------------------------------------------------------------------------
extern "C" void kernel_launch(void* const* d_in, const int* in_sizes, int n_in,
                              void* d_out, int out_size, void* d_ws, size_t ws_size,
                              hipStream_t stream) {
  (void)in_sizes; (void)n_in; (void)out_size; (void)ws_size;
  const float* tha  = (const float*)d_in[0];  // (2048,64)
  const float* stim = (const float*)d_in[1];  // (2048,128)
  const float* x    = (const float*)d_in[2];  // (2048,2048)
  const float* r    = (const float*)d_in[3];  // (2048,2048)
  const float* J    = (const float*)d_in[4];  // (2048,2048)
  const float* Bv   = (const float*)d_in[5];  // (1,2048)
  const float* U    = (const float*)d_in[6];  // (2048,64)
  const float* V    = (const float*)d_in[7];  // (64,2048)
  const float* Ist  = (const float*)d_in[8];  // (128,2048)
  const float* eps  = (const float*)d_in[9];  // (2048,2048)

  unsigned short* Apk = (unsigned short*)d_ws;            // 2048*2176 bf16 (8.5 MB)
  unsigned short* Bpk = Apk + (size_t)NN * KA;            // 2048*2240 bf16 (9.2 MB)
  float* part = (float*)(Bpk + (size_t)NN * KB);          // 4*2048*64 fp32 (2 MB)
  float* outx = (float*)d_out;
  float* outr = outx + (size_t)NN * NN;

  prep<<<1536, 256, 0, stream>>>(J, Ist, r, stim, U, V, Apk, Bpk, part);
  main_gemm<<<1024, 256, 0, stream>>>(Apk, Bpk, part, tha, x, eps, Bv,
                                      outx, outr);
}

// Round 8
// 196.291 us; speedup vs baseline: 1.0040x; 1.0040x over previous
//
#include <hip/hip_runtime.h>
#include <cstdint>
#include <cstddef>

// ---------------------------------------------------------------------------
// ThalamicRNN step. FP32 in/out; internal GEMM bf16 MFMA + fp32 accum.
//   A'  = [ r | stim ]           (2048 x 2176) bf16   (KA = 2176)
//   B'  = [ J^T | I_stim^T | U ] (2048 x 2240) bf16   (KB = 2240)
//   t[b,p] = tha[b,p] * (r @ V^T)[b,p]  -- split-K partials in prep,
//            reduced per-block inside main_gemm as the final K-tile vs U.
//   acc = A'@B'^T (+ t@U^T); x_new = x + (DT/TAU)*(-x+acc+B+SIG*eps);
//   r_new = softplus(x_new)
// Round 13: cross-round matrix isolated the binding variable: independent
// blocks/CU + barrier-group width (flow changes move time the WRONG way;
// BK=128 halving iters regressed 30%). Untried extreme: 32x64 tiles,
// 128 threads (2 waves, each the verified 32x32 acc[2][2] wave code),
// 2048 blocks = 8/CU, 12 KB LDS single-buffer, plain __syncthreads
// (counted-vmcnt was null in R3). B-panel L2 flow doubles -- proven slack.
// Bijective XCD swizzle: each XCD owns 32mt x 8nt, n-inner.
// prep byte-identical (passed R4/R6/R7).
// ---------------------------------------------------------------------------

#define KA 2176
#define KB 2240
#define NN 2048

using frag_ab = __attribute__((ext_vector_type(8))) short;   // 8 bf16
using frag_cd = __attribute__((ext_vector_type(4))) float;   // 4 fp32

__device__ __forceinline__ unsigned short f2bf(float f) {
  union { float f; unsigned int i; } v;
  v.f = f;
  unsigned int r = v.i + 0x7fffu + ((v.i >> 16) & 1u);  // RNE
  return (unsigned short)(r >> 16);
}

__device__ __forceinline__ uint4 cvt8(const float* __restrict__ p) {
  float4 a = *(const float4*)p;
  float4 b = *(const float4*)(p + 4);
  union { uint4 v; unsigned short u[8]; } d;
  d.u[0] = f2bf(a.x); d.u[1] = f2bf(a.y); d.u[2] = f2bf(a.z); d.u[3] = f2bf(a.w);
  d.u[4] = f2bf(b.x); d.u[5] = f2bf(b.y); d.u[6] = f2bf(b.z); d.u[7] = f2bf(b.w);
  return d.v;
}

// async global->LDS, 16 B/lane; LDS dest = wave-uniform base + lane*16.
__device__ __forceinline__ void gl_lds16(const void* g, void* l) {
  __builtin_amdgcn_global_load_lds(
      (const __attribute__((address_space(1))) void*)g,
      (__attribute__((address_space(3))) void*)l, 16, 0, 0);
}

// ---------------------------------------------------------------------------
// prep: blocks [0,1024)     J transpose -> Bp cols [0,2048)
//       [1024,1088)         I_stim transpose -> Bp cols [2048,2176)
//       [1088,1216)         stim -> Ap cols [2048,2176)   (128 blocks)
//       [1216,1280)         U -> Bp cols [2176,2240)      (64 blocks)
//       [1280,1536)         t split-K partials part[s][b][p] fp32,
//                           FUSED with r -> Ap cols [0,2048) bf16 pack
// ---------------------------------------------------------------------------
__global__ __launch_bounds__(256) void prep(
    const float* __restrict__ J, const float* __restrict__ Ist,
    const float* __restrict__ rg, const float* __restrict__ stim,
    const float* __restrict__ U, const float* __restrict__ V,
    unsigned short* __restrict__ Ap, unsigned short* __restrict__ Bp,
    float* __restrict__ part) {
  __shared__ unsigned short tile[64 * 66];
  __shared__ alignas(16) unsigned short Ats[32 * 64];
  __shared__ alignas(16) unsigned short Bts[64 * 64];
  const int blk = blockIdx.x;
  const int t = threadIdx.x;

  if (blk < 1088) {                      // ---- transposes ----
    const float* src;
    int dst_off, cx, cy;
    if (blk < 1024) { src = J;   dst_off = 0;    cx = blk & 31; cy = blk >> 5; }
    else            { src = Ist; dst_off = 2048; cx = (blk - 1024) & 31; cy = (blk - 1024) >> 5; }
    const int r0 = cy * 64, c0 = cx * 64;
    const int sr = t >> 3, c8 = t & 7;
#pragma unroll
    for (int p = 0; p < 2; ++p) {
      const int row = sr + 32 * p;
      union { uint4 v; unsigned short u[8]; } d;
      d.v = cvt8(&src[(size_t)(r0 + row) * 2048 + c0 + c8 * 8]);
#pragma unroll
      for (int e = 0; e < 8; ++e) tile[row * 66 + c8 * 8 + e] = d.u[e];
    }
    __syncthreads();
#pragma unroll
    for (int p = 0; p < 2; ++p) {
      const int scol = sr + 32 * p;
      union { uint4 v; unsigned short u[8]; } d;
#pragma unroll
      for (int e = 0; e < 8; ++e) d.u[e] = tile[(c8 * 8 + e) * 66 + scol];
      *(uint4*)&Bp[(size_t)(c0 + scol) * KB + dst_off + r0 + c8 * 8] = d.v;
    }
  } else if (blk < 1216) {               // ---- stim -> Ap[2048:2176) ----
    const int row = (blk - 1088) * 16 + (t >> 4);   // 16 rows/block
    const int ch  = t & 15;                         // 16 chunks of 8 floats
    *(uint4*)&Ap[(size_t)row * KA + 2048 + ch * 8] =
        cvt8(&stim[(size_t)row * 128 + ch * 8]);
  } else if (blk < 1280) {               // ---- U -> Bp[2176:2240) ----
    const int row = (blk - 1216) * 32 + (t >> 3);   // 32 rows/block
    const int ch  = t & 7;                          // 8 chunks of 8 floats
    *(uint4*)&Bp[(size_t)row * KB + 2176 + ch * 8] =
        cvt8(&U[(size_t)row * 64 + ch * 8]);
  } else {                               // ---- t split-K partials + r-pack ----
    const int tb = blk - 1280;
    const int mt = tb & 63, s = tb >> 6;
    const int b0 = mt * 32;
    const int wave = t >> 6, lane = t & 63;
    const int q = lane >> 4, l15 = lane & 15;
    const int arow = t >> 3, ac8 = t & 7;

    const float* gA  = rg + (size_t)(b0 + arow) * 2048 + s * 512 + ac8 * 8;
    const float* gB0 = V  + (size_t)arow        * 2048 + s * 512 + ac8 * 8;
    const float* gB1 = V  + (size_t)(arow + 32) * 2048 + s * 512 + ac8 * 8;
    // fused r->Ap pack destination (same elements this block converts)
    unsigned short* pAp = Ap + (size_t)(b0 + arow) * KA + s * 512 + ac8 * 8;

    frag_cd acc0 = {0.f, 0.f, 0.f, 0.f};
    frag_cd acc1 = {0.f, 0.f, 0.f, 0.f};

    for (int kt = 0; kt < 8; ++kt) {
      const int k0 = kt * 64;
      uint4 va  = cvt8(gA + k0);
      uint4 vb0 = cvt8(gB0 + k0);
      uint4 vb1 = cvt8(gB1 + k0);
      *(uint4*)&pAp[k0] = va;          // by-product: Ap bf16 pack
      __syncthreads();
      *(uint4*)&Ats[t * 8]        = va;
      *(uint4*)&Bts[t * 8]        = vb0;
      *(uint4*)&Bts[2048 + t * 8] = vb1;
      __syncthreads();
#pragma unroll
      for (int ks = 0; ks < 2; ++ks) {
        frag_ab a0 = *(const frag_ab*)&Ats[(l15)      * 64 + ks * 32 + q * 8];
        frag_ab a1 = *(const frag_ab*)&Ats[(16 + l15) * 64 + ks * 32 + q * 8];
        frag_ab b  = *(const frag_ab*)&Bts[(wave * 16 + l15) * 64 + ks * 32 + q * 8];
        acc0 = __builtin_amdgcn_mfma_f32_16x16x32_bf16(a0, b, acc0, 0, 0, 0);
        acc1 = __builtin_amdgcn_mfma_f32_16x16x32_bf16(a1, b, acc1, 0, 0, 0);
      }
    }
    const int p = wave * 16 + l15;
#pragma unroll
    for (int reg = 0; reg < 4; ++reg) {
      const int m0 = q * 4 + reg;   // C/D: row = quad*4+reg, col = lane&15
      part[((size_t)s * 2048 + b0 + m0) * 64 + p]      = acc0[reg];
      part[((size_t)s * 2048 + b0 + m0 + 16) * 64 + p] = acc1[reg];
    }
  }
}

// ---------------------------------------------------------------------------
// Main GEMM + fused t-reduce + epilogue. 32x64 tile (BM=32 batch rows,
// BN=64 neurons), BK=64, 128 threads (2 waves, each 32x32, acc[2][2],
// wm=0, wn=wave*32). 2048 blocks = 8/CU; 12 KB LDS single-buffer.
// 34 K-iters: sync -> 6x global_load_lds (2A+4B) -> sync -> 2 ks x 4 MFMA.
// Peeled 35th tile: t (from regs, 32x64) vs U. 8-chunk XOR swizzle
// (lc=(ci&7)^(row&7), read chunk ^ l7). Bijective XCD swizzle: each XCD
// owns 32(mt) x 8(nt) tiles, n-inner.
// ---------------------------------------------------------------------------
__global__ __launch_bounds__(128, 4) void main_gemm(
    const unsigned short* __restrict__ Ap, const unsigned short* __restrict__ Bp,
    const float* __restrict__ part, const float* __restrict__ tha,
    const float* __restrict__ xg, const float* __restrict__ epsg,
    const float* __restrict__ Bvec,
    float* __restrict__ outx, float* __restrict__ outr) {
  __shared__ alignas(16) unsigned short As[32 * 64];   // 4 KB
  __shared__ alignas(16) unsigned short Bs[64 * 64];   // 8 KB

  const int t = threadIdx.x;
  const int wave = t >> 6, lane = t & 63;
  const int q = lane >> 4, l15 = lane & 15, l7 = lane & 7;
  const int wn = wave * 32;                           // wave n-offset (wm = 0)

  // XCD swizzle: 2048 blocks, 8 XCDs; each owns 32(mt) x 8(nt), n-inner.
  const int bid = blockIdx.x;
  const int xcd = bid & 7, idx = bid >> 3;            // idx 0..255
  const int mt = ((xcd >> 2) << 5) + (idx >> 3);      // 0..63
  const int nt = ((xcd & 3) << 3) + (idx & 7);        // 0..31
  const int bm0 = mt * 32, bn0 = nt * 64;

  // ---- A staging (2 slots/thread) + fused t-tile reduce -------------------
  // slot ci holds row=ci>>3 (0..31), logical chunk (ci&7)^(row&7)
  const unsigned short* gA[2];
  uint4 tval[2];
#pragma unroll
  for (int r = 0; r < 2; ++r) {
    const int ci = r * 128 + t;
    const int row = ci >> 3;                 // 0..31
    const int lc = (ci & 7) ^ (row & 7);
    gA[r] = Ap + (size_t)(bm0 + row) * KA + lc * 8;

    // t[bm0+row][p0..p0+8) = tha * sum_s part[s]
    const int p0 = lc * 8;
    const size_t base = ((size_t)(bm0 + row)) * 64 + p0;
    float4 s0 = *(const float4*)&part[base];
    float4 s1 = *(const float4*)&part[base + 4];
#pragma unroll
    for (int s = 1; s < 4; ++s) {
      float4 a = *(const float4*)&part[(size_t)s * 131072 + base];
      float4 b = *(const float4*)&part[(size_t)s * 131072 + base + 4];
      s0.x += a.x; s0.y += a.y; s0.z += a.z; s0.w += a.w;
      s1.x += b.x; s1.y += b.y; s1.z += b.z; s1.w += b.w;
    }
    float4 th0 = *(const float4*)&tha[base];
    float4 th1 = *(const float4*)&tha[base + 4];
    union { uint4 v; unsigned short u[8]; } d;
    d.u[0] = f2bf(th0.x * s0.x); d.u[1] = f2bf(th0.y * s0.y);
    d.u[2] = f2bf(th0.z * s0.z); d.u[3] = f2bf(th0.w * s0.w);
    d.u[4] = f2bf(th1.x * s1.x); d.u[5] = f2bf(th1.y * s1.y);
    d.u[6] = f2bf(th1.z * s1.z); d.u[7] = f2bf(th1.w * s1.w);
    tval[r] = d.v;
  }

  // ---- B staging (4 slots/thread) -----------------------------------------
  const unsigned short* gB[4];
#pragma unroll
  for (int r = 0; r < 4; ++r) {
    const int ci = r * 128 + t;
    const int row = ci >> 3;                 // 0..63
    const int lc = (ci & 7) ^ (row & 7);
    gB[r] = Bp + (size_t)(bn0 + row) * KB + lc * 8;
  }

  frag_cd acc[2][2];
#pragma unroll
  for (int i = 0; i < 2; ++i)
#pragma unroll
    for (int j = 0; j < 2; ++j) {
      frag_cd z = {0.f, 0.f, 0.f, 0.f};
      acc[i][j] = z;
    }

#pragma unroll 1
  for (int kt = 0; kt < 34; ++kt) {   // A' has exactly 34 K-tiles (2176)
    const int k0 = kt * 64;
    __syncthreads();                  // all waves done reading previous tile
#pragma unroll
    for (int r = 0; r < 2; ++r)
      gl_lds16(gA[r] + k0, &As[(size_t)(r * 128 + wave * 64) * 8]);
#pragma unroll
    for (int r = 0; r < 4; ++r)
      gl_lds16(gB[r] + k0, &Bs[(size_t)(r * 128 + wave * 64) * 8]);
    __syncthreads();                  // compiler drains vmcnt before barrier
#pragma unroll
    for (int ks = 0; ks < 2; ++ks) {
      const int lc = ks * 4 + q;
      frag_ab af[2], bfr[2];
#pragma unroll
      for (int i = 0; i < 2; ++i) {
        af[i]  = *(const frag_ab*)&As[(i * 16 + l15) * 64 + ((lc ^ l7) * 8)];
        bfr[i] = *(const frag_ab*)&Bs[(wn + i * 16 + l15) * 64 + ((lc ^ l7) * 8)];
      }
#pragma unroll
      for (int i = 0; i < 2; ++i)
#pragma unroll
        for (int j = 0; j < 2; ++j)
          acc[i][j] = __builtin_amdgcn_mfma_f32_16x16x32_bf16(af[i], bfr[j], acc[i][j], 0, 0, 0);
    }
  }

  // ---- peeled K-tile: A-side = t (from regs, 32x64), B-side = U -----------
  {
    __syncthreads();
#pragma unroll
    for (int r = 0; r < 2; ++r)
      *(uint4*)&As[(size_t)(r * 128 + t) * 8] = tval[r];
#pragma unroll
    for (int r = 0; r < 4; ++r)
      gl_lds16(gB[r] + 2176, &Bs[(size_t)(r * 128 + wave * 64) * 8]);
    __syncthreads();
#pragma unroll
    for (int ks = 0; ks < 2; ++ks) {
      const int lc = ks * 4 + q;
      frag_ab af[2], bfr[2];
#pragma unroll
      for (int i = 0; i < 2; ++i) {
        af[i]  = *(const frag_ab*)&As[(i * 16 + l15) * 64 + ((lc ^ l7) * 8)];
        bfr[i] = *(const frag_ab*)&Bs[(wn + i * 16 + l15) * 64 + ((lc ^ l7) * 8)];
      }
#pragma unroll
      for (int i = 0; i < 2; ++i)
#pragma unroll
        for (int j = 0; j < 2; ++j)
          acc[i][j] = __builtin_amdgcn_mfma_f32_16x16x32_bf16(af[i], bfr[j], acc[i][j], 0, 0, 0);
    }
  }

  // ---- epilogue: fp32 direct from accumulator C-layout -------------------
  const float A_DT = 0.33333334f;          // DT/TAU
  const float SIG  = 0.81649658092772615f; // sqrt(2*DT/TAU)
#pragma unroll
  for (int j = 0; j < 2; ++j) {
    const int nc = bn0 + wn + j * 16 + l15;    // C/D col = lane&15
    const float bvf = Bvec[nc];
#pragma unroll
    for (int i = 0; i < 2; ++i) {
#pragma unroll
      for (int reg = 0; reg < 4; ++reg) {
        const int mr = bm0 + i * 16 + q * 4 + reg;  // C/D row = quad*4+reg
        const size_t off = (size_t)mr * NN + nc;
        const float xf = xg[off];
        const float ef = epsg[off];
        const float xn = xf + A_DT * (acc[i][j][reg] + bvf - xf + SIG * ef);
        outx[off] = xn;
        outr[off] = (xn > 20.f) ? xn : log1pf(__expf(xn));
      }
    }
  }
}

// ---------------------------------------------------------------------------
extern "C" void kernel_launch(void* const* d_in, const int* in_sizes, int n_in,
                              void* d_out, int out_size, void* d_ws, size_t ws_size,
                              hipStream_t stream) {
  (void)in_sizes; (void)n_in; (void)out_size; (void)ws_size;
  const float* tha  = (const float*)d_in[0];  // (2048,64)
  const float* stim = (const float*)d_in[1];  // (2048,128)
  const float* x    = (const float*)d_in[2];  // (2048,2048)
  const float* r    = (const float*)d_in[3];  // (2048,2048)
  const float* J    = (const float*)d_in[4];  // (2048,2048)
  const float* Bv   = (const float*)d_in[5];  // (1,2048)
  const float* U    = (const float*)d_in[6];  // (2048,64)
  const float* V    = (const float*)d_in[7];  // (64,2048)
  const float* Ist  = (const float*)d_in[8];  // (128,2048)
  const float* eps  = (const float*)d_in[9];  // (2048,2048)

  unsigned short* Apk = (unsigned short*)d_ws;            // 2048*2176 bf16 (8.5 MB)
  unsigned short* Bpk = Apk + (size_t)NN * KA;            // 2048*2240 bf16 (9.2 MB)
  float* part = (float*)(Bpk + (size_t)NN * KB);          // 4*2048*64 fp32 (2 MB)
  float* outx = (float*)d_out;
  float* outr = outx + (size_t)NN * NN;

  prep<<<1536, 256, 0, stream>>>(J, Ist, r, stim, U, V, Apk, Bpk, part);
  main_gemm<<<2048, 128, 0, stream>>>(Apk, Bpk, part, tha, x, eps, Bv,
                                      outx, outr);
}

// Round 9
// 184.077 us; speedup vs baseline: 1.0706x; 1.0664x over previous
//
#include <hip/hip_runtime.h>
#include <cstdint>
#include <cstddef>

// ---------------------------------------------------------------------------
// ThalamicRNN step. FP32 in/out; internal GEMM bf16 MFMA + fp32 accum.
//   A'  = [ r | stim ]           (2048 x 2176) bf16   (KA = 2176)
//   B'  = [ J^T | I_stim^T | U ] (2048 x 2240) bf16   (KB = 2240)
//   t[b,p] = tha[b,p] * (r @ V^T)[b,p]  -- split-K partials in prep,
//            reduced per-block inside main_gemm as the final K-tile vs U.
//   acc = A'@B'^T (+ t@U^T); x_new = x + (DT/TAU)*(-x+acc+B+SIG*eps);
//   r_new = softplus(x_new)
// Round 14: sequential K-split of the verified R4 main (61.0 us). Two
// launches of the SAME 64x64/4-wave/dbuf/counted-vmcnt kernel body:
//   half-0 (mode 0): K-tiles 0..16, stores raw fp32 acc into the outx
//           region (pure-GEMM dispatch -- first clean GEMM measurement).
//   half-1 (mode 1): K-tiles 17..33 + t/U peel, adds half-0's partial,
//           full epilogue. In-place p0==outx (no restrict; store depends
//           on the p0 load, so ordering is enforced by data dependence).
// Per-XCD operand panel halves 6.8 -> 3.4 MB (< 4 MB L2) -- tests the
// last un-falsified footprint theory. prep unchanged (passed R4/R6/R7/R8).
// ---------------------------------------------------------------------------

#define KA 2176
#define KB 2240
#define NN 2048

using frag_ab = __attribute__((ext_vector_type(8))) short;   // 8 bf16
using frag_cd = __attribute__((ext_vector_type(4))) float;   // 4 fp32

__device__ __forceinline__ unsigned short f2bf(float f) {
  union { float f; unsigned int i; } v;
  v.f = f;
  unsigned int r = v.i + 0x7fffu + ((v.i >> 16) & 1u);  // RNE
  return (unsigned short)(r >> 16);
}

__device__ __forceinline__ uint4 cvt8(const float* __restrict__ p) {
  float4 a = *(const float4*)p;
  float4 b = *(const float4*)(p + 4);
  union { uint4 v; unsigned short u[8]; } d;
  d.u[0] = f2bf(a.x); d.u[1] = f2bf(a.y); d.u[2] = f2bf(a.z); d.u[3] = f2bf(a.w);
  d.u[4] = f2bf(b.x); d.u[5] = f2bf(b.y); d.u[6] = f2bf(b.z); d.u[7] = f2bf(b.w);
  return d.v;
}

// async global->LDS, 16 B/lane; LDS dest = wave-uniform base + lane*16.
__device__ __forceinline__ void gl_lds16(const void* g, void* l) {
  __builtin_amdgcn_global_load_lds(
      (const __attribute__((address_space(1))) void*)g,
      (__attribute__((address_space(3))) void*)l, 16, 0, 0);
}

// ---------------------------------------------------------------------------
// prep: blocks [0,1024)     J transpose -> Bp cols [0,2048)
//       [1024,1088)         I_stim transpose -> Bp cols [2048,2176)
//       [1088,1216)         stim -> Ap cols [2048,2176)   (128 blocks)
//       [1216,1280)         U -> Bp cols [2176,2240)      (64 blocks)
//       [1280,1536)         t split-K partials part[s][b][p] fp32,
//                           FUSED with r -> Ap cols [0,2048) bf16 pack
// ---------------------------------------------------------------------------
__global__ __launch_bounds__(256) void prep(
    const float* __restrict__ J, const float* __restrict__ Ist,
    const float* __restrict__ rg, const float* __restrict__ stim,
    const float* __restrict__ U, const float* __restrict__ V,
    unsigned short* __restrict__ Ap, unsigned short* __restrict__ Bp,
    float* __restrict__ part) {
  __shared__ unsigned short tile[64 * 66];
  __shared__ alignas(16) unsigned short Ats[32 * 64];
  __shared__ alignas(16) unsigned short Bts[64 * 64];
  const int blk = blockIdx.x;
  const int t = threadIdx.x;

  if (blk < 1088) {                      // ---- transposes ----
    const float* src;
    int dst_off, cx, cy;
    if (blk < 1024) { src = J;   dst_off = 0;    cx = blk & 31; cy = blk >> 5; }
    else            { src = Ist; dst_off = 2048; cx = (blk - 1024) & 31; cy = (blk - 1024) >> 5; }
    const int r0 = cy * 64, c0 = cx * 64;
    const int sr = t >> 3, c8 = t & 7;
#pragma unroll
    for (int p = 0; p < 2; ++p) {
      const int row = sr + 32 * p;
      union { uint4 v; unsigned short u[8]; } d;
      d.v = cvt8(&src[(size_t)(r0 + row) * 2048 + c0 + c8 * 8]);
#pragma unroll
      for (int e = 0; e < 8; ++e) tile[row * 66 + c8 * 8 + e] = d.u[e];
    }
    __syncthreads();
#pragma unroll
    for (int p = 0; p < 2; ++p) {
      const int scol = sr + 32 * p;
      union { uint4 v; unsigned short u[8]; } d;
#pragma unroll
      for (int e = 0; e < 8; ++e) d.u[e] = tile[(c8 * 8 + e) * 66 + scol];
      *(uint4*)&Bp[(size_t)(c0 + scol) * KB + dst_off + r0 + c8 * 8] = d.v;
    }
  } else if (blk < 1216) {               // ---- stim -> Ap[2048:2176) ----
    const int row = (blk - 1088) * 16 + (t >> 4);   // 16 rows/block
    const int ch  = t & 15;                         // 16 chunks of 8 floats
    *(uint4*)&Ap[(size_t)row * KA + 2048 + ch * 8] =
        cvt8(&stim[(size_t)row * 128 + ch * 8]);
  } else if (blk < 1280) {               // ---- U -> Bp[2176:2240) ----
    const int row = (blk - 1216) * 32 + (t >> 3);   // 32 rows/block
    const int ch  = t & 7;                          // 8 chunks of 8 floats
    *(uint4*)&Bp[(size_t)row * KB + 2176 + ch * 8] =
        cvt8(&U[(size_t)row * 64 + ch * 8]);
  } else {                               // ---- t split-K partials + r-pack ----
    const int tb = blk - 1280;
    const int mt = tb & 63, s = tb >> 6;
    const int b0 = mt * 32;
    const int wave = t >> 6, lane = t & 63;
    const int q = lane >> 4, l15 = lane & 15;
    const int arow = t >> 3, ac8 = t & 7;

    const float* gA  = rg + (size_t)(b0 + arow) * 2048 + s * 512 + ac8 * 8;
    const float* gB0 = V  + (size_t)arow        * 2048 + s * 512 + ac8 * 8;
    const float* gB1 = V  + (size_t)(arow + 32) * 2048 + s * 512 + ac8 * 8;
    // fused r->Ap pack destination (same elements this block converts)
    unsigned short* pAp = Ap + (size_t)(b0 + arow) * KA + s * 512 + ac8 * 8;

    frag_cd acc0 = {0.f, 0.f, 0.f, 0.f};
    frag_cd acc1 = {0.f, 0.f, 0.f, 0.f};

    for (int kt = 0; kt < 8; ++kt) {
      const int k0 = kt * 64;
      uint4 va  = cvt8(gA + k0);
      uint4 vb0 = cvt8(gB0 + k0);
      uint4 vb1 = cvt8(gB1 + k0);
      *(uint4*)&pAp[k0] = va;          // by-product: Ap bf16 pack
      __syncthreads();
      *(uint4*)&Ats[t * 8]        = va;
      *(uint4*)&Bts[t * 8]        = vb0;
      *(uint4*)&Bts[2048 + t * 8] = vb1;
      __syncthreads();
#pragma unroll
      for (int ks = 0; ks < 2; ++ks) {
        frag_ab a0 = *(const frag_ab*)&Ats[(l15)      * 64 + ks * 32 + q * 8];
        frag_ab a1 = *(const frag_ab*)&Ats[(16 + l15) * 64 + ks * 32 + q * 8];
        frag_ab b  = *(const frag_ab*)&Bts[(wave * 16 + l15) * 64 + ks * 32 + q * 8];
        acc0 = __builtin_amdgcn_mfma_f32_16x16x32_bf16(a0, b, acc0, 0, 0, 0);
        acc1 = __builtin_amdgcn_mfma_f32_16x16x32_bf16(a1, b, acc1, 0, 0, 0);
      }
    }
    const int p = wave * 16 + l15;
#pragma unroll
    for (int reg = 0; reg < 4; ++reg) {
      const int m0 = q * 4 + reg;   // C/D: row = quad*4+reg, col = lane&15
      part[((size_t)s * 2048 + b0 + m0) * 64 + p]      = acc0[reg];
      part[((size_t)s * 2048 + b0 + m0 + 16) * 64 + p] = acc1[reg];
    }
  }
}

// ---------------------------------------------------------------------------
// Main GEMM half + fused t-reduce + epilogue. 64x64 tile, BK=64, 256 threads
// (4 waves, each 32x32, acc[2][2]). Verified R4 dbuf body (counted vmcnt),
// K-range parameterized: 17 iters from kt0. mode 0: store raw fp32 acc to
// pout. mode 1: peel t/U tile, add p0 partial, full epilogue.
// XCD swizzle: 16m x 8n region per XCD, n-inner. 4 blocks/CU.
// ---------------------------------------------------------------------------
__global__ __launch_bounds__(256, 4) void main_gemm(
    const unsigned short* __restrict__ Ap, const unsigned short* __restrict__ Bp,
    const float* __restrict__ part, const float* __restrict__ tha,
    const float* __restrict__ xg, const float* __restrict__ epsg,
    const float* __restrict__ Bvec,
    float* outx, float* __restrict__ outr,
    const float* p0, float* pout, const int kt0, const int mode) {
  __shared__ alignas(16) unsigned short As[2][64 * 64];   // 2 x 8 KB
  __shared__ alignas(16) unsigned short Bs[2][64 * 64];   // 2 x 8 KB

  const int t = threadIdx.x;
  const int wave = t >> 6, lane = t & 63;
  const int q = lane >> 4, l15 = lane & 15, l7 = lane & 7;
  const int wm = (wave & 1) * 32, wn = (wave >> 1) * 32;

  // XCD swizzle: 1024 blocks, 8 XCDs, each owns 16(m) x 8(n) tiles, n-inner.
  const int bid = blockIdx.x;
  const int xcd = bid & 7, idx = bid >> 3;                 // idx 0..127
  const int mt = ((xcd >> 2) << 4) + (idx >> 3);           // 0..31
  const int nt = ((xcd & 3) << 3) + (idx & 7);             // 0..31
  const int bm0 = mt * 64, bn0 = nt * 64;

  // staging slots: slot ci (16B units) holds row=ci>>3, logical chunk (ci&7)^(row&7)
  const unsigned short* gA[2];
  const unsigned short* gB[2];
  uint4 tval[2] = {{0u, 0u, 0u, 0u}, {0u, 0u, 0u, 0u}};
#pragma unroll
  for (int r = 0; r < 2; ++r) {
    const int ci = r * 256 + t;
    const int row = ci >> 3;
    const int lc = (ci & 7) ^ (row & 7);
    gA[r] = Ap + (size_t)(bm0 + row) * KA + lc * 8;
    gB[r] = Bp + (size_t)(bn0 + row) * KB + lc * 8;

    if (mode) {
      // ---- t-tile: t[bm0+row][p0c..p0c+8) = tha * sum_s part[s] ----
      const int p0c = lc * 8;
      const size_t base = ((size_t)(bm0 + row)) * 64 + p0c;
      float4 s0 = *(const float4*)&part[base];
      float4 s1 = *(const float4*)&part[base + 4];
#pragma unroll
      for (int s = 1; s < 4; ++s) {
        float4 a = *(const float4*)&part[(size_t)s * 131072 + base];
        float4 b = *(const float4*)&part[(size_t)s * 131072 + base + 4];
        s0.x += a.x; s0.y += a.y; s0.z += a.z; s0.w += a.w;
        s1.x += b.x; s1.y += b.y; s1.z += b.z; s1.w += b.w;
      }
      float4 th0 = *(const float4*)&tha[base];
      float4 th1 = *(const float4*)&tha[base + 4];
      union { uint4 v; unsigned short u[8]; } d;
      d.u[0] = f2bf(th0.x * s0.x); d.u[1] = f2bf(th0.y * s0.y);
      d.u[2] = f2bf(th0.z * s0.z); d.u[3] = f2bf(th0.w * s0.w);
      d.u[4] = f2bf(th1.x * s1.x); d.u[5] = f2bf(th1.y * s1.y);
      d.u[6] = f2bf(th1.z * s1.z); d.u[7] = f2bf(th1.w * s1.w);
      tval[r] = d.v;
    }
  }

  frag_cd acc[2][2];
#pragma unroll
  for (int i = 0; i < 2; ++i)
#pragma unroll
    for (int j = 0; j < 2; ++j) {
      frag_cd z = {0.f, 0.f, 0.f, 0.f};
      acc[i][j] = z;
    }

  // ---- prologue: drain everything, then stage K-tile kt0 into buf 0 ----
  asm volatile("s_waitcnt vmcnt(0)" ::: "memory");
  {
    const int k0 = kt0 * 64;
#pragma unroll
    for (int r = 0; r < 2; ++r) {
      gl_lds16(gA[r] + k0, &As[0][(size_t)(r * 256 + wave * 64) * 8]);
      gl_lds16(gB[r] + k0, &Bs[0][(size_t)(r * 256 + wave * 64) * 8]);
    }
  }

#pragma unroll 1
  for (int kt = 0; kt < 17; ++kt) {  // this half covers tiles kt0..kt0+16
    const int cur = kt & 1;
    // barrier 1: all waves done reading buf[cur^1] -> safe to overwrite
    asm volatile("s_waitcnt lgkmcnt(0)" ::: "memory");
    __builtin_amdgcn_s_barrier();
    __builtin_amdgcn_sched_barrier(0);
    if (kt < 16) {
      const int k0n = (kt0 + kt + 1) * 64;
      unsigned short* dA = &As[cur ^ 1][0];
      unsigned short* dB = &Bs[cur ^ 1][0];
#pragma unroll
      for (int r = 0; r < 2; ++r) {
        gl_lds16(gA[r] + k0n, dA + (size_t)(r * 256 + wave * 64) * 8);
        gl_lds16(gB[r] + k0n, dB + (size_t)(r * 256 + wave * 64) * 8);
      }
      // 8 outstanding; drain exactly tile kt's 4, keep tile kt+1's 4 in flight
      asm volatile("s_waitcnt vmcnt(4)" ::: "memory");
    } else if (mode) {
      // peeled-tile staging: A-side = t from regs, B-side = U (k0 = 2176)
      unsigned short* dA = &As[cur ^ 1][0];
      unsigned short* dB = &Bs[cur ^ 1][0];
#pragma unroll
      for (int r = 0; r < 2; ++r) {
        *(uint4*)&dA[(size_t)(r * 256 + t) * 8] = tval[r];
        gl_lds16(gB[r] + 34 * 64, dB + (size_t)(r * 256 + wave * 64) * 8);
      }
      // 6 outstanding; drain tile's 4, keep the 2 U loads in flight;
      // lgkmcnt(0) drains the tval ds_writes
      asm volatile("s_waitcnt vmcnt(2) lgkmcnt(0)" ::: "memory");
    } else {
      // mode 0, last tile: nothing more to stage, drain current tile fully
      asm volatile("s_waitcnt vmcnt(0)" ::: "memory");
    }
    // barrier 2: buf[cur] fully staged by all waves
    __builtin_amdgcn_s_barrier();
    __builtin_amdgcn_sched_barrier(0);
    const unsigned short* cA = &As[cur][0];
    const unsigned short* cB = &Bs[cur][0];
#pragma unroll
    for (int ks = 0; ks < 2; ++ks) {
      const int lc = ks * 4 + q;
      frag_ab af[2], bfr[2];
#pragma unroll
      for (int i = 0; i < 2; ++i) {
        af[i]  = *(const frag_ab*)&cA[(wm + i * 16 + l15) * 64 + ((lc ^ l7) * 8)];
        bfr[i] = *(const frag_ab*)&cB[(wn + i * 16 + l15) * 64 + ((lc ^ l7) * 8)];
      }
#pragma unroll
      for (int i = 0; i < 2; ++i)
#pragma unroll
        for (int j = 0; j < 2; ++j)
          acc[i][j] = __builtin_amdgcn_mfma_f32_16x16x32_bf16(af[i], bfr[j], acc[i][j], 0, 0, 0);
    }
  }

  if (mode) {
    // ---- peeled K-tile compute: staged at kt=16 into buf 1 ----
    asm volatile("s_waitcnt vmcnt(0) lgkmcnt(0)" ::: "memory");
    __builtin_amdgcn_s_barrier();
    __builtin_amdgcn_sched_barrier(0);
    const unsigned short* cA = &As[1][0];
    const unsigned short* cB = &Bs[1][0];
#pragma unroll
    for (int ks = 0; ks < 2; ++ks) {
      const int lc = ks * 4 + q;
      frag_ab af[2], bfr[2];
#pragma unroll
      for (int i = 0; i < 2; ++i) {
        af[i]  = *(const frag_ab*)&cA[(wm + i * 16 + l15) * 64 + ((lc ^ l7) * 8)];
        bfr[i] = *(const frag_ab*)&cB[(wn + i * 16 + l15) * 64 + ((lc ^ l7) * 8)];
      }
#pragma unroll
      for (int i = 0; i < 2; ++i)
#pragma unroll
        for (int j = 0; j < 2; ++j)
          acc[i][j] = __builtin_amdgcn_mfma_f32_16x16x32_bf16(af[i], bfr[j], acc[i][j], 0, 0, 0);
    }

    // ---- epilogue: add half-0 partial, then fp32 epilogue ------------------
    const float A_DT = 0.33333334f;          // DT/TAU
    const float SIG  = 0.81649658092772615f; // sqrt(2*DT/TAU)
#pragma unroll
    for (int j = 0; j < 2; ++j) {
      const int nc = bn0 + wn + j * 16 + l15;    // C/D col = lane&15
      const float bvf = Bvec[nc];
#pragma unroll
      for (int i = 0; i < 2; ++i) {
#pragma unroll
        for (int reg = 0; reg < 4; ++reg) {
          const int mr = bm0 + wm + i * 16 + q * 4 + reg;  // C/D row = quad*4+reg
          const size_t off = (size_t)mr * NN + nc;
          const float pv = p0[off];      // half-0 partial (aliases outx; store
                                         // below depends on this load)
          const float xf = xg[off];
          const float ef = epsg[off];
          const float xn =
              xf + A_DT * (acc[i][j][reg] + pv + bvf - xf + SIG * ef);
          outx[off] = xn;
          outr[off] = (xn > 20.f) ? xn : log1pf(__expf(xn));
        }
      }
    }
  } else {
    // ---- mode 0: store raw fp32 partial ------------------------------------
#pragma unroll
    for (int j = 0; j < 2; ++j) {
      const int nc = bn0 + wn + j * 16 + l15;
#pragma unroll
      for (int i = 0; i < 2; ++i) {
#pragma unroll
        for (int reg = 0; reg < 4; ++reg) {
          const int mr = bm0 + wm + i * 16 + q * 4 + reg;
          pout[(size_t)mr * NN + nc] = acc[i][j][reg];
        }
      }
    }
  }
}

// ---------------------------------------------------------------------------
extern "C" void kernel_launch(void* const* d_in, const int* in_sizes, int n_in,
                              void* d_out, int out_size, void* d_ws, size_t ws_size,
                              hipStream_t stream) {
  (void)in_sizes; (void)n_in; (void)out_size; (void)ws_size;
  const float* tha  = (const float*)d_in[0];  // (2048,64)
  const float* stim = (const float*)d_in[1];  // (2048,128)
  const float* x    = (const float*)d_in[2];  // (2048,2048)
  const float* r    = (const float*)d_in[3];  // (2048,2048)
  const float* J    = (const float*)d_in[4];  // (2048,2048)
  const float* Bv   = (const float*)d_in[5];  // (1,2048)
  const float* U    = (const float*)d_in[6];  // (2048,64)
  const float* V    = (const float*)d_in[7];  // (64,2048)
  const float* Ist  = (const float*)d_in[8];  // (128,2048)
  const float* eps  = (const float*)d_in[9];  // (2048,2048)

  unsigned short* Apk = (unsigned short*)d_ws;            // 2048*2176 bf16 (8.5 MB)
  unsigned short* Bpk = Apk + (size_t)NN * KA;            // 2048*2240 bf16 (9.2 MB)
  float* part = (float*)(Bpk + (size_t)NN * KB);          // 4*2048*64 fp32 (2 MB)
  float* outx = (float*)d_out;
  float* outr = outx + (size_t)NN * NN;

  prep<<<1536, 256, 0, stream>>>(J, Ist, r, stim, U, V, Apk, Bpk, part);
  // half-0: K-tiles 0..16, pure GEMM, partial -> outx region
  main_gemm<<<1024, 256, 0, stream>>>(Apk, Bpk, part, tha, x, eps, Bv,
                                      outx, outr, nullptr, outx, 0, 0);
  // half-1: K-tiles 17..33 + t/U peel, + partial, full epilogue (in place)
  main_gemm<<<1024, 256, 0, stream>>>(Apk, Bpk, part, tha, x, eps, Bv,
                                      outx, outr, outx, nullptr, 17, 1);
}

// Round 10
// 171.496 us; speedup vs baseline: 1.1492x; 1.0734x over previous
//
#include <hip/hip_runtime.h>
#include <cstdint>
#include <cstddef>

// ---------------------------------------------------------------------------
// ThalamicRNN step. FP32 in/out; internal GEMM bf16 MFMA + fp32 accum.
//   A'  = [ r | stim ]           (2048 x 2176) bf16   (KA = 2176)
//   B'  = [ J^T | I_stim^T | U ] (2048 x 2240) bf16   (KB = 2240)
//   t[b,p] = tha[b,p] * (r @ V^T)[b,p]  -- split-K partials in prep,
//            reduced per-block inside main_gemm as the final K-tile vs U.
//   acc = A'@B'^T (+ t@U^T); x_new = x + (DT/TAU)*(-x+acc+B+SIG*eps);
//   r_new = softplus(x_new)
// Round 15: R9's split decomposed the 61 us fused main into GEMM ~32 us
// (0.95 us/iter, latency-structural) + epilogue ~29 us (67 MB at only
// 2.3 TB/s -- scattered 64-B fragment stores, outx/outr interleaved).
// This round: GEMM keeps the R4 dbuf body but stores raw fp32 acc to the
// outx region (measured path, half-0); a DEDICATED grid-stride float4
// epilogue kernel (m13 streaming pattern, 1KB/wave segments) does
// acc+x+eps -> outx/outr. 84 MB at ~5 TB/s predicted ~17 us, vs 29 fused.
// prep unchanged (passed R4/R6/R7/R8/R9).
// ---------------------------------------------------------------------------

#define KA 2176
#define KB 2240
#define NN 2048

using frag_ab = __attribute__((ext_vector_type(8))) short;   // 8 bf16
using frag_cd = __attribute__((ext_vector_type(4))) float;   // 4 fp32

__device__ __forceinline__ unsigned short f2bf(float f) {
  union { float f; unsigned int i; } v;
  v.f = f;
  unsigned int r = v.i + 0x7fffu + ((v.i >> 16) & 1u);  // RNE
  return (unsigned short)(r >> 16);
}

__device__ __forceinline__ uint4 cvt8(const float* __restrict__ p) {
  float4 a = *(const float4*)p;
  float4 b = *(const float4*)(p + 4);
  union { uint4 v; unsigned short u[8]; } d;
  d.u[0] = f2bf(a.x); d.u[1] = f2bf(a.y); d.u[2] = f2bf(a.z); d.u[3] = f2bf(a.w);
  d.u[4] = f2bf(b.x); d.u[5] = f2bf(b.y); d.u[6] = f2bf(b.z); d.u[7] = f2bf(b.w);
  return d.v;
}

// async global->LDS, 16 B/lane; LDS dest = wave-uniform base + lane*16.
__device__ __forceinline__ void gl_lds16(const void* g, void* l) {
  __builtin_amdgcn_global_load_lds(
      (const __attribute__((address_space(1))) void*)g,
      (__attribute__((address_space(3))) void*)l, 16, 0, 0);
}

// ---------------------------------------------------------------------------
// prep: blocks [0,1024)     J transpose -> Bp cols [0,2048)
//       [1024,1088)         I_stim transpose -> Bp cols [2048,2176)
//       [1088,1216)         stim -> Ap cols [2048,2176)   (128 blocks)
//       [1216,1280)         U -> Bp cols [2176,2240)      (64 blocks)
//       [1280,1536)         t split-K partials part[s][b][p] fp32,
//                           FUSED with r -> Ap cols [0,2048) bf16 pack
// ---------------------------------------------------------------------------
__global__ __launch_bounds__(256) void prep(
    const float* __restrict__ J, const float* __restrict__ Ist,
    const float* __restrict__ rg, const float* __restrict__ stim,
    const float* __restrict__ U, const float* __restrict__ V,
    unsigned short* __restrict__ Ap, unsigned short* __restrict__ Bp,
    float* __restrict__ part) {
  __shared__ unsigned short tile[64 * 66];
  __shared__ alignas(16) unsigned short Ats[32 * 64];
  __shared__ alignas(16) unsigned short Bts[64 * 64];
  const int blk = blockIdx.x;
  const int t = threadIdx.x;

  if (blk < 1088) {                      // ---- transposes ----
    const float* src;
    int dst_off, cx, cy;
    if (blk < 1024) { src = J;   dst_off = 0;    cx = blk & 31; cy = blk >> 5; }
    else            { src = Ist; dst_off = 2048; cx = (blk - 1024) & 31; cy = (blk - 1024) >> 5; }
    const int r0 = cy * 64, c0 = cx * 64;
    const int sr = t >> 3, c8 = t & 7;
#pragma unroll
    for (int p = 0; p < 2; ++p) {
      const int row = sr + 32 * p;
      union { uint4 v; unsigned short u[8]; } d;
      d.v = cvt8(&src[(size_t)(r0 + row) * 2048 + c0 + c8 * 8]);
#pragma unroll
      for (int e = 0; e < 8; ++e) tile[row * 66 + c8 * 8 + e] = d.u[e];
    }
    __syncthreads();
#pragma unroll
    for (int p = 0; p < 2; ++p) {
      const int scol = sr + 32 * p;
      union { uint4 v; unsigned short u[8]; } d;
#pragma unroll
      for (int e = 0; e < 8; ++e) d.u[e] = tile[(c8 * 8 + e) * 66 + scol];
      *(uint4*)&Bp[(size_t)(c0 + scol) * KB + dst_off + r0 + c8 * 8] = d.v;
    }
  } else if (blk < 1216) {               // ---- stim -> Ap[2048:2176) ----
    const int row = (blk - 1088) * 16 + (t >> 4);   // 16 rows/block
    const int ch  = t & 15;                         // 16 chunks of 8 floats
    *(uint4*)&Ap[(size_t)row * KA + 2048 + ch * 8] =
        cvt8(&stim[(size_t)row * 128 + ch * 8]);
  } else if (blk < 1280) {               // ---- U -> Bp[2176:2240) ----
    const int row = (blk - 1216) * 32 + (t >> 3);   // 32 rows/block
    const int ch  = t & 7;                          // 8 chunks of 8 floats
    *(uint4*)&Bp[(size_t)row * KB + 2176 + ch * 8] =
        cvt8(&U[(size_t)row * 64 + ch * 8]);
  } else {                               // ---- t split-K partials + r-pack ----
    const int tb = blk - 1280;
    const int mt = tb & 63, s = tb >> 6;
    const int b0 = mt * 32;
    const int wave = t >> 6, lane = t & 63;
    const int q = lane >> 4, l15 = lane & 15;
    const int arow = t >> 3, ac8 = t & 7;

    const float* gA  = rg + (size_t)(b0 + arow) * 2048 + s * 512 + ac8 * 8;
    const float* gB0 = V  + (size_t)arow        * 2048 + s * 512 + ac8 * 8;
    const float* gB1 = V  + (size_t)(arow + 32) * 2048 + s * 512 + ac8 * 8;
    // fused r->Ap pack destination (same elements this block converts)
    unsigned short* pAp = Ap + (size_t)(b0 + arow) * KA + s * 512 + ac8 * 8;

    frag_cd acc0 = {0.f, 0.f, 0.f, 0.f};
    frag_cd acc1 = {0.f, 0.f, 0.f, 0.f};

    for (int kt = 0; kt < 8; ++kt) {
      const int k0 = kt * 64;
      uint4 va  = cvt8(gA + k0);
      uint4 vb0 = cvt8(gB0 + k0);
      uint4 vb1 = cvt8(gB1 + k0);
      *(uint4*)&pAp[k0] = va;          // by-product: Ap bf16 pack
      __syncthreads();
      *(uint4*)&Ats[t * 8]        = va;
      *(uint4*)&Bts[t * 8]        = vb0;
      *(uint4*)&Bts[2048 + t * 8] = vb1;
      __syncthreads();
#pragma unroll
      for (int ks = 0; ks < 2; ++ks) {
        frag_ab a0 = *(const frag_ab*)&Ats[(l15)      * 64 + ks * 32 + q * 8];
        frag_ab a1 = *(const frag_ab*)&Ats[(16 + l15) * 64 + ks * 32 + q * 8];
        frag_ab b  = *(const frag_ab*)&Bts[(wave * 16 + l15) * 64 + ks * 32 + q * 8];
        acc0 = __builtin_amdgcn_mfma_f32_16x16x32_bf16(a0, b, acc0, 0, 0, 0);
        acc1 = __builtin_amdgcn_mfma_f32_16x16x32_bf16(a1, b, acc1, 0, 0, 0);
      }
    }
    const int p = wave * 16 + l15;
#pragma unroll
    for (int reg = 0; reg < 4; ++reg) {
      const int m0 = q * 4 + reg;   // C/D: row = quad*4+reg, col = lane&15
      part[((size_t)s * 2048 + b0 + m0) * 64 + p]      = acc0[reg];
      part[((size_t)s * 2048 + b0 + m0 + 16) * 64 + p] = acc1[reg];
    }
  }
}

// ---------------------------------------------------------------------------
// Pure GEMM + fused t-reduce: 64x64 tile, BK=64, 256 threads (4 waves,
// each 32x32, acc[2][2]). R4's verified dbuf body (counted vmcnt), 34
// K-iters + t/U peel; epilogue REPLACED by raw fp32 acc store into accout
// (the measured half-0 store path). XCD swizzle 16m x 8n. 4 blocks/CU.
// ---------------------------------------------------------------------------
__global__ __launch_bounds__(256, 4) void main_gemm(
    const unsigned short* __restrict__ Ap, const unsigned short* __restrict__ Bp,
    const float* __restrict__ part, const float* __restrict__ tha,
    float* __restrict__ accout) {
  __shared__ alignas(16) unsigned short As[2][64 * 64];   // 2 x 8 KB
  __shared__ alignas(16) unsigned short Bs[2][64 * 64];   // 2 x 8 KB

  const int t = threadIdx.x;
  const int wave = t >> 6, lane = t & 63;
  const int q = lane >> 4, l15 = lane & 15, l7 = lane & 7;
  const int wm = (wave & 1) * 32, wn = (wave >> 1) * 32;

  // XCD swizzle: 1024 blocks, 8 XCDs, each owns 16(m) x 8(n) tiles, n-inner.
  const int bid = blockIdx.x;
  const int xcd = bid & 7, idx = bid >> 3;                 // idx 0..127
  const int mt = ((xcd >> 2) << 4) + (idx >> 3);           // 0..31
  const int nt = ((xcd & 3) << 3) + (idx & 7);             // 0..31
  const int bm0 = mt * 64, bn0 = nt * 64;

  // staging slots: slot ci (16B units) holds row=ci>>3, logical chunk (ci&7)^(row&7)
  const unsigned short* gA[2];
  const unsigned short* gB[2];
  uint4 tval[2];                 // this thread's two t-tile slots (bf16 x8)
#pragma unroll
  for (int r = 0; r < 2; ++r) {
    const int ci = r * 256 + t;
    const int row = ci >> 3;
    const int lc = (ci & 7) ^ (row & 7);
    gA[r] = Ap + (size_t)(bm0 + row) * KA + lc * 8;
    gB[r] = Bp + (size_t)(bn0 + row) * KB + lc * 8;

    // ---- t-tile: t[bm0+row][p0..p0+8) = tha * sum_s part[s] ----
    const int p0 = lc * 8;
    const size_t base = ((size_t)(bm0 + row)) * 64 + p0;
    float4 s0 = *(const float4*)&part[base];
    float4 s1 = *(const float4*)&part[base + 4];
#pragma unroll
    for (int s = 1; s < 4; ++s) {
      float4 a = *(const float4*)&part[(size_t)s * 131072 + base];
      float4 b = *(const float4*)&part[(size_t)s * 131072 + base + 4];
      s0.x += a.x; s0.y += a.y; s0.z += a.z; s0.w += a.w;
      s1.x += b.x; s1.y += b.y; s1.z += b.z; s1.w += b.w;
    }
    float4 th0 = *(const float4*)&tha[base];
    float4 th1 = *(const float4*)&tha[base + 4];
    union { uint4 v; unsigned short u[8]; } d;
    d.u[0] = f2bf(th0.x * s0.x); d.u[1] = f2bf(th0.y * s0.y);
    d.u[2] = f2bf(th0.z * s0.z); d.u[3] = f2bf(th0.w * s0.w);
    d.u[4] = f2bf(th1.x * s1.x); d.u[5] = f2bf(th1.y * s1.y);
    d.u[6] = f2bf(th1.z * s1.z); d.u[7] = f2bf(th1.w * s1.w);
    tval[r] = d.v;
  }

  frag_cd acc[2][2];
#pragma unroll
  for (int i = 0; i < 2; ++i)
#pragma unroll
    for (int j = 0; j < 2; ++j) {
      frag_cd z = {0.f, 0.f, 0.f, 0.f};
      acc[i][j] = z;
    }

  // ---- prologue: drain everything, then stage K-tile 0 into buf 0 ----
  asm volatile("s_waitcnt vmcnt(0)" ::: "memory");
#pragma unroll
  for (int r = 0; r < 2; ++r) {
    gl_lds16(gA[r], &As[0][(size_t)(r * 256 + wave * 64) * 8]);
    gl_lds16(gB[r], &Bs[0][(size_t)(r * 256 + wave * 64) * 8]);
  }

#pragma unroll 1
  for (int kt = 0; kt < 34; ++kt) {  // A' has exactly 34 K-tiles (2176)
    const int cur = kt & 1;
    // barrier 1: all waves done reading buf[cur^1] -> safe to overwrite
    asm volatile("s_waitcnt lgkmcnt(0)" ::: "memory");
    __builtin_amdgcn_s_barrier();
    __builtin_amdgcn_sched_barrier(0);
    if (kt < 33) {
      const int k0n = (kt + 1) * 64;
      unsigned short* dA = &As[cur ^ 1][0];
      unsigned short* dB = &Bs[cur ^ 1][0];
#pragma unroll
      for (int r = 0; r < 2; ++r) {
        gl_lds16(gA[r] + k0n, dA + (size_t)(r * 256 + wave * 64) * 8);
        gl_lds16(gB[r] + k0n, dB + (size_t)(r * 256 + wave * 64) * 8);
      }
      // 8 outstanding; drain exactly tile kt's 4, keep tile kt+1's 4 in flight
      asm volatile("s_waitcnt vmcnt(4)" ::: "memory");
    } else {
      // peeled-tile staging: A-side = t from regs, B-side = U (k0 = 2176)
      unsigned short* dA = &As[cur ^ 1][0];
      unsigned short* dB = &Bs[cur ^ 1][0];
#pragma unroll
      for (int r = 0; r < 2; ++r) {
        *(uint4*)&dA[(size_t)(r * 256 + t) * 8] = tval[r];
        gl_lds16(gB[r] + 34 * 64, dB + (size_t)(r * 256 + wave * 64) * 8);
      }
      // 6 outstanding; drain tile 33's 4, keep the 2 U loads in flight;
      // lgkmcnt(0) drains the tval ds_writes
      asm volatile("s_waitcnt vmcnt(2) lgkmcnt(0)" ::: "memory");
    }
    // barrier 2: buf[cur] fully staged by all waves
    __builtin_amdgcn_s_barrier();
    __builtin_amdgcn_sched_barrier(0);
    const unsigned short* cA = &As[cur][0];
    const unsigned short* cB = &Bs[cur][0];
#pragma unroll
    for (int ks = 0; ks < 2; ++ks) {
      const int lc = ks * 4 + q;
      frag_ab af[2], bfr[2];
#pragma unroll
      for (int i = 0; i < 2; ++i) {
        af[i]  = *(const frag_ab*)&cA[(wm + i * 16 + l15) * 64 + ((lc ^ l7) * 8)];
        bfr[i] = *(const frag_ab*)&cB[(wn + i * 16 + l15) * 64 + ((lc ^ l7) * 8)];
      }
#pragma unroll
      for (int i = 0; i < 2; ++i)
#pragma unroll
        for (int j = 0; j < 2; ++j)
          acc[i][j] = __builtin_amdgcn_mfma_f32_16x16x32_bf16(af[i], bfr[j], acc[i][j], 0, 0, 0);
    }
  }

  // ---- peeled K-tile 34 compute: staged into buf 0 at kt=33 ----
  {
    asm volatile("s_waitcnt vmcnt(0) lgkmcnt(0)" ::: "memory");
    __builtin_amdgcn_s_barrier();
    __builtin_amdgcn_sched_barrier(0);
    const unsigned short* cA = &As[0][0];
    const unsigned short* cB = &Bs[0][0];
#pragma unroll
    for (int ks = 0; ks < 2; ++ks) {
      const int lc = ks * 4 + q;
      frag_ab af[2], bfr[2];
#pragma unroll
      for (int i = 0; i < 2; ++i) {
        af[i]  = *(const frag_ab*)&cA[(wm + i * 16 + l15) * 64 + ((lc ^ l7) * 8)];
        bfr[i] = *(const frag_ab*)&cB[(wn + i * 16 + l15) * 64 + ((lc ^ l7) * 8)];
      }
#pragma unroll
      for (int i = 0; i < 2; ++i)
#pragma unroll
        for (int j = 0; j < 2; ++j)
          acc[i][j] = __builtin_amdgcn_mfma_f32_16x16x32_bf16(af[i], bfr[j], acc[i][j], 0, 0, 0);
    }
  }

  // ---- store raw fp32 accumulator (measured half-0 path) -----------------
#pragma unroll
  for (int j = 0; j < 2; ++j) {
    const int nc = bn0 + wn + j * 16 + l15;        // C/D col = lane&15
#pragma unroll
    for (int i = 0; i < 2; ++i) {
#pragma unroll
      for (int reg = 0; reg < 4; ++reg) {
        const int mr = bm0 + wm + i * 16 + q * 4 + reg;  // C/D row = quad*4+reg
        accout[(size_t)mr * NN + nc] = acc[i][j][reg];
      }
    }
  }
}

// ---------------------------------------------------------------------------
// Streaming epilogue (m13 pattern): grid-stride float4, consecutive threads
// -> consecutive 16B -> 1KB/wave segments. outx in-place: read acc, write
// x_new (same address, thread-local dependence). 2048 blocks x 256 threads,
// 2 quads/thread.
// ---------------------------------------------------------------------------
__global__ __launch_bounds__(256) void epilogue(
    const float* __restrict__ xg, const float* __restrict__ epsg,
    const float* __restrict__ Bvec,
    float* outx /* acc in, x_new out */, float* __restrict__ outr) {
  const float A_DT = 0.33333334f;          // DT/TAU
  const float SIG  = 0.81649658092772615f; // sqrt(2*DT/TAU)
  const int NQ = (NN * NN) / 4;            // 1,048,576 float4 quads
  const int tid = blockIdx.x * 256 + threadIdx.x;
#pragma unroll 1
  for (int idx = tid; idx < NQ; idx += 2048 * 256) {
    const size_t o = (size_t)idx * 4;
    float4 av = *(const float4*)&outx[o];
    float4 xv = *(const float4*)&xg[o];
    float4 ev = *(const float4*)&epsg[o];
    float4 bv = *(const float4*)&Bvec[o & 2047];   // col = o mod 2048

    float4 xn;
    xn.x = xv.x + A_DT * (av.x + bv.x - xv.x + SIG * ev.x);
    xn.y = xv.y + A_DT * (av.y + bv.y - xv.y + SIG * ev.y);
    xn.z = xv.z + A_DT * (av.z + bv.z - xv.z + SIG * ev.z);
    xn.w = xv.w + A_DT * (av.w + bv.w - xv.w + SIG * ev.w);

    float4 rn;
    rn.x = (xn.x > 20.f) ? xn.x : log1pf(__expf(xn.x));
    rn.y = (xn.y > 20.f) ? xn.y : log1pf(__expf(xn.y));
    rn.z = (xn.z > 20.f) ? xn.z : log1pf(__expf(xn.z));
    rn.w = (xn.w > 20.f) ? xn.w : log1pf(__expf(xn.w));

    *(float4*)&outx[o] = xn;
    *(float4*)&outr[o] = rn;
  }
}

// ---------------------------------------------------------------------------
extern "C" void kernel_launch(void* const* d_in, const int* in_sizes, int n_in,
                              void* d_out, int out_size, void* d_ws, size_t ws_size,
                              hipStream_t stream) {
  (void)in_sizes; (void)n_in; (void)out_size; (void)ws_size;
  const float* tha  = (const float*)d_in[0];  // (2048,64)
  const float* stim = (const float*)d_in[1];  // (2048,128)
  const float* x    = (const float*)d_in[2];  // (2048,2048)
  const float* r    = (const float*)d_in[3];  // (2048,2048)
  const float* J    = (const float*)d_in[4];  // (2048,2048)
  const float* Bv   = (const float*)d_in[5];  // (1,2048)
  const float* U    = (const float*)d_in[6];  // (2048,64)
  const float* V    = (const float*)d_in[7];  // (64,2048)
  const float* Ist  = (const float*)d_in[8];  // (128,2048)
  const float* eps  = (const float*)d_in[9];  // (2048,2048)

  unsigned short* Apk = (unsigned short*)d_ws;            // 2048*2176 bf16 (8.5 MB)
  unsigned short* Bpk = Apk + (size_t)NN * KA;            // 2048*2240 bf16 (9.2 MB)
  float* part = (float*)(Bpk + (size_t)NN * KB);          // 4*2048*64 fp32 (2 MB)
  float* outx = (float*)d_out;
  float* outr = outx + (size_t)NN * NN;

  prep<<<1536, 256, 0, stream>>>(J, Ist, r, stim, U, V, Apk, Bpk, part);
  // pure GEMM (+ t/U peel): raw fp32 acc -> outx region
  main_gemm<<<1024, 256, 0, stream>>>(Apk, Bpk, part, tha, outx);
  // streaming epilogue: acc+x+eps -> x_new (in place) + softplus -> outr
  epilogue<<<2048, 256, 0, stream>>>(x, eps, Bv, outx, outr);
}

// Round 11
// 170.919 us; speedup vs baseline: 1.1530x; 1.0034x over previous
//
#include <hip/hip_runtime.h>
#include <cstdint>
#include <cstddef>

// ---------------------------------------------------------------------------
// ThalamicRNN step. FP32 in/out; internal GEMM bf16 MFMA + fp32 accum.
//   A'  = [ r | stim ]           (2048 x 2176) bf16   (KA = 2176)
//   B'  = [ J^T | I_stim^T | U ] (2048 x 2240) bf16   (KB = 2240)
//   t[b,p] = tha[b,p] * (r @ V^T)[b,p]  -- split-K partials in prep,
//            reduced per-block inside main_gemm as the final K-tile vs U.
//   acc = A'@B'^T (+ t@U^T); x_new = x + (DT/TAU)*(-x+acc+B+SIG*eps);
//   r_new = softplus(x_new)
// Round 16: R10's split proved the fused epilogue was REQUEST-RATE bound
// (16x scalar dword ops/thread, 64-B segments), not BW-bound. This round
// re-fuses the epilogue into main_gemm with coalesced access: acc tile ->
// LDS (reuse the 32KB As dbuf after the last MFMA), read back as float4
// rows, float4 x/eps loads + outx/outr stores (256-B/quarter-wave).
// Eliminates the 33.6 MB acc round-trip AND the separate epilogue launch.
// vmem ops/thread 80 -> 16. GEMM body unchanged (R4 dbuf, counted vmcnt,
// XCD swizzle). prep unchanged (passed R4/R6/R7/R8/R9/R10).
// ---------------------------------------------------------------------------

#define KA 2176
#define KB 2240
#define NN 2048

using frag_ab = __attribute__((ext_vector_type(8))) short;   // 8 bf16
using frag_cd = __attribute__((ext_vector_type(4))) float;   // 4 fp32

__device__ __forceinline__ unsigned short f2bf(float f) {
  union { float f; unsigned int i; } v;
  v.f = f;
  unsigned int r = v.i + 0x7fffu + ((v.i >> 16) & 1u);  // RNE
  return (unsigned short)(r >> 16);
}

__device__ __forceinline__ uint4 cvt8(const float* __restrict__ p) {
  float4 a = *(const float4*)p;
  float4 b = *(const float4*)(p + 4);
  union { uint4 v; unsigned short u[8]; } d;
  d.u[0] = f2bf(a.x); d.u[1] = f2bf(a.y); d.u[2] = f2bf(a.z); d.u[3] = f2bf(a.w);
  d.u[4] = f2bf(b.x); d.u[5] = f2bf(b.y); d.u[6] = f2bf(b.z); d.u[7] = f2bf(b.w);
  return d.v;
}

// async global->LDS, 16 B/lane; LDS dest = wave-uniform base + lane*16.
__device__ __forceinline__ void gl_lds16(const void* g, void* l) {
  __builtin_amdgcn_global_load_lds(
      (const __attribute__((address_space(1))) void*)g,
      (__attribute__((address_space(3))) void*)l, 16, 0, 0);
}

// ---------------------------------------------------------------------------
// prep: blocks [0,1024)     J transpose -> Bp cols [0,2048)
//       [1024,1088)         I_stim transpose -> Bp cols [2048,2176)
//       [1088,1216)         stim -> Ap cols [2048,2176)   (128 blocks)
//       [1216,1280)         U -> Bp cols [2176,2240)      (64 blocks)
//       [1280,1536)         t split-K partials part[s][b][p] fp32,
//                           FUSED with r -> Ap cols [0,2048) bf16 pack
// ---------------------------------------------------------------------------
__global__ __launch_bounds__(256) void prep(
    const float* __restrict__ J, const float* __restrict__ Ist,
    const float* __restrict__ rg, const float* __restrict__ stim,
    const float* __restrict__ U, const float* __restrict__ V,
    unsigned short* __restrict__ Ap, unsigned short* __restrict__ Bp,
    float* __restrict__ part) {
  __shared__ unsigned short tile[64 * 66];
  __shared__ alignas(16) unsigned short Ats[32 * 64];
  __shared__ alignas(16) unsigned short Bts[64 * 64];
  const int blk = blockIdx.x;
  const int t = threadIdx.x;

  if (blk < 1088) {                      // ---- transposes ----
    const float* src;
    int dst_off, cx, cy;
    if (blk < 1024) { src = J;   dst_off = 0;    cx = blk & 31; cy = blk >> 5; }
    else            { src = Ist; dst_off = 2048; cx = (blk - 1024) & 31; cy = (blk - 1024) >> 5; }
    const int r0 = cy * 64, c0 = cx * 64;
    const int sr = t >> 3, c8 = t & 7;
#pragma unroll
    for (int p = 0; p < 2; ++p) {
      const int row = sr + 32 * p;
      union { uint4 v; unsigned short u[8]; } d;
      d.v = cvt8(&src[(size_t)(r0 + row) * 2048 + c0 + c8 * 8]);
#pragma unroll
      for (int e = 0; e < 8; ++e) tile[row * 66 + c8 * 8 + e] = d.u[e];
    }
    __syncthreads();
#pragma unroll
    for (int p = 0; p < 2; ++p) {
      const int scol = sr + 32 * p;
      union { uint4 v; unsigned short u[8]; } d;
#pragma unroll
      for (int e = 0; e < 8; ++e) d.u[e] = tile[(c8 * 8 + e) * 66 + scol];
      *(uint4*)&Bp[(size_t)(c0 + scol) * KB + dst_off + r0 + c8 * 8] = d.v;
    }
  } else if (blk < 1216) {               // ---- stim -> Ap[2048:2176) ----
    const int row = (blk - 1088) * 16 + (t >> 4);   // 16 rows/block
    const int ch  = t & 15;                         // 16 chunks of 8 floats
    *(uint4*)&Ap[(size_t)row * KA + 2048 + ch * 8] =
        cvt8(&stim[(size_t)row * 128 + ch * 8]);
  } else if (blk < 1280) {               // ---- U -> Bp[2176:2240) ----
    const int row = (blk - 1216) * 32 + (t >> 3);   // 32 rows/block
    const int ch  = t & 7;                          // 8 chunks of 8 floats
    *(uint4*)&Bp[(size_t)row * KB + 2176 + ch * 8] =
        cvt8(&U[(size_t)row * 64 + ch * 8]);
  } else {                               // ---- t split-K partials + r-pack ----
    const int tb = blk - 1280;
    const int mt = tb & 63, s = tb >> 6;
    const int b0 = mt * 32;
    const int wave = t >> 6, lane = t & 63;
    const int q = lane >> 4, l15 = lane & 15;
    const int arow = t >> 3, ac8 = t & 7;

    const float* gA  = rg + (size_t)(b0 + arow) * 2048 + s * 512 + ac8 * 8;
    const float* gB0 = V  + (size_t)arow        * 2048 + s * 512 + ac8 * 8;
    const float* gB1 = V  + (size_t)(arow + 32) * 2048 + s * 512 + ac8 * 8;
    // fused r->Ap pack destination (same elements this block converts)
    unsigned short* pAp = Ap + (size_t)(b0 + arow) * KA + s * 512 + ac8 * 8;

    frag_cd acc0 = {0.f, 0.f, 0.f, 0.f};
    frag_cd acc1 = {0.f, 0.f, 0.f, 0.f};

    for (int kt = 0; kt < 8; ++kt) {
      const int k0 = kt * 64;
      uint4 va  = cvt8(gA + k0);
      uint4 vb0 = cvt8(gB0 + k0);
      uint4 vb1 = cvt8(gB1 + k0);
      *(uint4*)&pAp[k0] = va;          // by-product: Ap bf16 pack
      __syncthreads();
      *(uint4*)&Ats[t * 8]        = va;
      *(uint4*)&Bts[t * 8]        = vb0;
      *(uint4*)&Bts[2048 + t * 8] = vb1;
      __syncthreads();
#pragma unroll
      for (int ks = 0; ks < 2; ++ks) {
        frag_ab a0 = *(const frag_ab*)&Ats[(l15)      * 64 + ks * 32 + q * 8];
        frag_ab a1 = *(const frag_ab*)&Ats[(16 + l15) * 64 + ks * 32 + q * 8];
        frag_ab b  = *(const frag_ab*)&Bts[(wave * 16 + l15) * 64 + ks * 32 + q * 8];
        acc0 = __builtin_amdgcn_mfma_f32_16x16x32_bf16(a0, b, acc0, 0, 0, 0);
        acc1 = __builtin_amdgcn_mfma_f32_16x16x32_bf16(a1, b, acc1, 0, 0, 0);
      }
    }
    const int p = wave * 16 + l15;
#pragma unroll
    for (int reg = 0; reg < 4; ++reg) {
      const int m0 = q * 4 + reg;   // C/D: row = quad*4+reg, col = lane&15
      part[((size_t)s * 2048 + b0 + m0) * 64 + p]      = acc0[reg];
      part[((size_t)s * 2048 + b0 + m0 + 16) * 64 + p] = acc1[reg];
    }
  }
}

// ---------------------------------------------------------------------------
// Main GEMM + fused t-reduce + COALESCED fused epilogue. 64x64 tile, BK=64,
// 256 threads (4 waves, each 32x32, acc[2][2]). R4 dbuf body (counted
// vmcnt), 34 K-iters + t/U peel. Epilogue: acc -> LDS fp32 tile (reuse As,
// 16 KB) -> float4 row reads -> float4 x/eps loads, update + softplus,
// float4 outx/outr stores (256-B per quarter-wave).
// XCD swizzle 16m x 8n. 4 blocks/CU.
// ---------------------------------------------------------------------------
__global__ __launch_bounds__(256, 4) void main_gemm(
    const unsigned short* __restrict__ Ap, const unsigned short* __restrict__ Bp,
    const float* __restrict__ part, const float* __restrict__ tha,
    const float* __restrict__ xg, const float* __restrict__ epsg,
    const float* __restrict__ Bvec,
    float* __restrict__ outx, float* __restrict__ outr) {
  __shared__ alignas(16) unsigned short As[2][64 * 64];   // 2 x 8 KB
  __shared__ alignas(16) unsigned short Bs[2][64 * 64];   // 2 x 8 KB

  const int t = threadIdx.x;
  const int wave = t >> 6, lane = t & 63;
  const int q = lane >> 4, l15 = lane & 15, l7 = lane & 7;
  const int wm = (wave & 1) * 32, wn = (wave >> 1) * 32;

  // XCD swizzle: 1024 blocks, 8 XCDs, each owns 16(m) x 8(n) tiles, n-inner.
  const int bid = blockIdx.x;
  const int xcd = bid & 7, idx = bid >> 3;                 // idx 0..127
  const int mt = ((xcd >> 2) << 4) + (idx >> 3);           // 0..31
  const int nt = ((xcd & 3) << 3) + (idx & 7);             // 0..31
  const int bm0 = mt * 64, bn0 = nt * 64;

  // staging slots: slot ci (16B units) holds row=ci>>3, logical chunk (ci&7)^(row&7)
  const unsigned short* gA[2];
  const unsigned short* gB[2];
  uint4 tval[2];                 // this thread's two t-tile slots (bf16 x8)
#pragma unroll
  for (int r = 0; r < 2; ++r) {
    const int ci = r * 256 + t;
    const int row = ci >> 3;
    const int lc = (ci & 7) ^ (row & 7);
    gA[r] = Ap + (size_t)(bm0 + row) * KA + lc * 8;
    gB[r] = Bp + (size_t)(bn0 + row) * KB + lc * 8;

    // ---- t-tile: t[bm0+row][p0..p0+8) = tha * sum_s part[s] ----
    const int p0 = lc * 8;
    const size_t base = ((size_t)(bm0 + row)) * 64 + p0;
    float4 s0 = *(const float4*)&part[base];
    float4 s1 = *(const float4*)&part[base + 4];
#pragma unroll
    for (int s = 1; s < 4; ++s) {
      float4 a = *(const float4*)&part[(size_t)s * 131072 + base];
      float4 b = *(const float4*)&part[(size_t)s * 131072 + base + 4];
      s0.x += a.x; s0.y += a.y; s0.z += a.z; s0.w += a.w;
      s1.x += b.x; s1.y += b.y; s1.z += b.z; s1.w += b.w;
    }
    float4 th0 = *(const float4*)&tha[base];
    float4 th1 = *(const float4*)&tha[base + 4];
    union { uint4 v; unsigned short u[8]; } d;
    d.u[0] = f2bf(th0.x * s0.x); d.u[1] = f2bf(th0.y * s0.y);
    d.u[2] = f2bf(th0.z * s0.z); d.u[3] = f2bf(th0.w * s0.w);
    d.u[4] = f2bf(th1.x * s1.x); d.u[5] = f2bf(th1.y * s1.y);
    d.u[6] = f2bf(th1.z * s1.z); d.u[7] = f2bf(th1.w * s1.w);
    tval[r] = d.v;
  }

  frag_cd acc[2][2];
#pragma unroll
  for (int i = 0; i < 2; ++i)
#pragma unroll
    for (int j = 0; j < 2; ++j) {
      frag_cd z = {0.f, 0.f, 0.f, 0.f};
      acc[i][j] = z;
    }

  // ---- prologue: drain everything, then stage K-tile 0 into buf 0 ----
  asm volatile("s_waitcnt vmcnt(0)" ::: "memory");
#pragma unroll
  for (int r = 0; r < 2; ++r) {
    gl_lds16(gA[r], &As[0][(size_t)(r * 256 + wave * 64) * 8]);
    gl_lds16(gB[r], &Bs[0][(size_t)(r * 256 + wave * 64) * 8]);
  }

#pragma unroll 1
  for (int kt = 0; kt < 34; ++kt) {  // A' has exactly 34 K-tiles (2176)
    const int cur = kt & 1;
    // barrier 1: all waves done reading buf[cur^1] -> safe to overwrite
    asm volatile("s_waitcnt lgkmcnt(0)" ::: "memory");
    __builtin_amdgcn_s_barrier();
    __builtin_amdgcn_sched_barrier(0);
    if (kt < 33) {
      const int k0n = (kt + 1) * 64;
      unsigned short* dA = &As[cur ^ 1][0];
      unsigned short* dB = &Bs[cur ^ 1][0];
#pragma unroll
      for (int r = 0; r < 2; ++r) {
        gl_lds16(gA[r] + k0n, dA + (size_t)(r * 256 + wave * 64) * 8);
        gl_lds16(gB[r] + k0n, dB + (size_t)(r * 256 + wave * 64) * 8);
      }
      // 8 outstanding; drain exactly tile kt's 4, keep tile kt+1's 4 in flight
      asm volatile("s_waitcnt vmcnt(4)" ::: "memory");
    } else {
      // peeled-tile staging: A-side = t from regs, B-side = U (k0 = 2176)
      unsigned short* dA = &As[cur ^ 1][0];
      unsigned short* dB = &Bs[cur ^ 1][0];
#pragma unroll
      for (int r = 0; r < 2; ++r) {
        *(uint4*)&dA[(size_t)(r * 256 + t) * 8] = tval[r];
        gl_lds16(gB[r] + 34 * 64, dB + (size_t)(r * 256 + wave * 64) * 8);
      }
      // 6 outstanding; drain tile 33's 4, keep the 2 U loads in flight;
      // lgkmcnt(0) drains the tval ds_writes
      asm volatile("s_waitcnt vmcnt(2) lgkmcnt(0)" ::: "memory");
    }
    // barrier 2: buf[cur] fully staged by all waves
    __builtin_amdgcn_s_barrier();
    __builtin_amdgcn_sched_barrier(0);
    const unsigned short* cA = &As[cur][0];
    const unsigned short* cB = &Bs[cur][0];
#pragma unroll
    for (int ks = 0; ks < 2; ++ks) {
      const int lc = ks * 4 + q;
      frag_ab af[2], bfr[2];
#pragma unroll
      for (int i = 0; i < 2; ++i) {
        af[i]  = *(const frag_ab*)&cA[(wm + i * 16 + l15) * 64 + ((lc ^ l7) * 8)];
        bfr[i] = *(const frag_ab*)&cB[(wn + i * 16 + l15) * 64 + ((lc ^ l7) * 8)];
      }
#pragma unroll
      for (int i = 0; i < 2; ++i)
#pragma unroll
        for (int j = 0; j < 2; ++j)
          acc[i][j] = __builtin_amdgcn_mfma_f32_16x16x32_bf16(af[i], bfr[j], acc[i][j], 0, 0, 0);
    }
  }

  // ---- peeled K-tile 34 compute: staged into buf 0 at kt=33 ----
  {
    asm volatile("s_waitcnt vmcnt(0) lgkmcnt(0)" ::: "memory");
    __builtin_amdgcn_s_barrier();
    __builtin_amdgcn_sched_barrier(0);
    const unsigned short* cA = &As[0][0];
    const unsigned short* cB = &Bs[0][0];
#pragma unroll
    for (int ks = 0; ks < 2; ++ks) {
      const int lc = ks * 4 + q;
      frag_ab af[2], bfr[2];
#pragma unroll
      for (int i = 0; i < 2; ++i) {
        af[i]  = *(const frag_ab*)&cA[(wm + i * 16 + l15) * 64 + ((lc ^ l7) * 8)];
        bfr[i] = *(const frag_ab*)&cB[(wn + i * 16 + l15) * 64 + ((lc ^ l7) * 8)];
      }
#pragma unroll
      for (int i = 0; i < 2; ++i)
#pragma unroll
        for (int j = 0; j < 2; ++j)
          acc[i][j] = __builtin_amdgcn_mfma_f32_16x16x32_bf16(af[i], bfr[j], acc[i][j], 0, 0, 0);
    }
  }

  // ---- fused coalesced epilogue -------------------------------------------
  // Stage the 64x64 fp32 acc tile into LDS (reuse As, 16 KB), then read back
  // as float4 rows: thread handles 4 quads f = w*256+t, row = f>>4,
  // col = (f&15)*4. Global: 256-B contiguous per quarter-wave.
  {
    float* ctile = (float*)&As[0][0];    // 16 KB fp32 scratch
    __syncthreads();                     // all LDS frag reads complete
#pragma unroll
    for (int j = 0; j < 2; ++j) {
      const int nc = wn + j * 16 + l15;          // C/D col = lane&15
#pragma unroll
      for (int i = 0; i < 2; ++i) {
#pragma unroll
        for (int reg = 0; reg < 4; ++reg) {
          const int mr = wm + i * 16 + q * 4 + reg;  // C/D row = quad*4+reg
          ctile[mr * 64 + nc] = acc[i][j][reg];
        }
      }
    }
    __syncthreads();

    const float A_DT = 0.33333334f;          // DT/TAU
    const float SIG  = 0.81649658092772615f; // sqrt(2*DT/TAU)
#pragma unroll
    for (int w = 0; w < 4; ++w) {
      const int f = w * 256 + t;               // 0..1023
      const int row = f >> 4;                  // 0..63
      const int c4 = (f & 15) * 4;             // 0..60
      float4 av = *(const float4*)&ctile[row * 64 + c4];
      const size_t off = (size_t)(bm0 + row) * NN + bn0 + c4;
      float4 xv = *(const float4*)&xg[off];
      float4 ev = *(const float4*)&epsg[off];
      float4 bv = *(const float4*)&Bvec[bn0 + c4];

      float4 xn;
      xn.x = xv.x + A_DT * (av.x + bv.x - xv.x + SIG * ev.x);
      xn.y = xv.y + A_DT * (av.y + bv.y - xv.y + SIG * ev.y);
      xn.z = xv.z + A_DT * (av.z + bv.z - xv.z + SIG * ev.z);
      xn.w = xv.w + A_DT * (av.w + bv.w - xv.w + SIG * ev.w);

      float4 rn;
      rn.x = (xn.x > 20.f) ? xn.x : log1pf(__expf(xn.x));
      rn.y = (xn.y > 20.f) ? xn.y : log1pf(__expf(xn.y));
      rn.z = (xn.z > 20.f) ? xn.z : log1pf(__expf(xn.z));
      rn.w = (xn.w > 20.f) ? xn.w : log1pf(__expf(xn.w));

      *(float4*)&outx[off] = xn;
      *(float4*)&outr[off] = rn;
    }
  }
}

// ---------------------------------------------------------------------------
extern "C" void kernel_launch(void* const* d_in, const int* in_sizes, int n_in,
                              void* d_out, int out_size, void* d_ws, size_t ws_size,
                              hipStream_t stream) {
  (void)in_sizes; (void)n_in; (void)out_size; (void)ws_size;
  const float* tha  = (const float*)d_in[0];  // (2048,64)
  const float* stim = (const float*)d_in[1];  // (2048,128)
  const float* x    = (const float*)d_in[2];  // (2048,2048)
  const float* r    = (const float*)d_in[3];  // (2048,2048)
  const float* J    = (const float*)d_in[4];  // (2048,2048)
  const float* Bv   = (const float*)d_in[5];  // (1,2048)
  const float* U    = (const float*)d_in[6];  // (2048,64)
  const float* V    = (const float*)d_in[7];  // (64,2048)
  const float* Ist  = (const float*)d_in[8];  // (128,2048)
  const float* eps  = (const float*)d_in[9];  // (2048,2048)

  unsigned short* Apk = (unsigned short*)d_ws;            // 2048*2176 bf16 (8.5 MB)
  unsigned short* Bpk = Apk + (size_t)NN * KA;            // 2048*2240 bf16 (9.2 MB)
  float* part = (float*)(Bpk + (size_t)NN * KB);          // 4*2048*64 fp32 (2 MB)
  float* outx = (float*)d_out;
  float* outr = outx + (size_t)NN * NN;

  prep<<<1536, 256, 0, stream>>>(J, Ist, r, stim, U, V, Apk, Bpk, part);
  main_gemm<<<1024, 256, 0, stream>>>(Apk, Bpk, part, tha, x, eps, Bv,
                                      outx, outr);
}

// Round 12
// 170.492 us; speedup vs baseline: 1.1559x; 1.0025x over previous
//
#include <hip/hip_runtime.h>
#include <cstdint>
#include <cstddef>

// ---------------------------------------------------------------------------
// ThalamicRNN step. FP32 in/out; internal GEMM bf16 MFMA + fp32 accum.
//   A'  = [ r | stim ]           (2048 x 2176) bf16   (KA = 2176)
//   B'  = [ J^T | I_stim^T | U ] (2048 x 2240) bf16   (KB = 2240)
//   t[b,p] = tha[b,p] * (r @ V^T)[b,p]  -- split-K partials in prep,
//            reduced per-block inside main_gemm as the final K-tile vs U.
//   acc = A'@B'^T (+ t@U^T); x_new = x + (DT/TAU)*(-x+acc+B+SIG*eps);
//   r_new = softplus(x_new)
// Round 17: R10 split structure (GEMM 32.6 us profiled + streaming
// epilogue) with a hardware softplus: log1pf (libm software polynomial,
// ~20 VALU ops/elem) -> __logf(1+__expf(x)) (2 HW TRANS ops). R10's
// epilogue ran at only 3.8 TB/s of the 6.3 ceiling despite perfect
// coalescing -- TRANS/VALU-throttled. Epilogue also restructured to
// exactly 4 unrolled stride-262144 passes (1024x256x4 quads = NQ) for
// 4 independent memory streams/thread. GEMM + prep byte-identical to R10.
// ---------------------------------------------------------------------------

#define KA 2176
#define KB 2240
#define NN 2048

using frag_ab = __attribute__((ext_vector_type(8))) short;   // 8 bf16
using frag_cd = __attribute__((ext_vector_type(4))) float;   // 4 fp32

__device__ __forceinline__ unsigned short f2bf(float f) {
  union { float f; unsigned int i; } v;
  v.f = f;
  unsigned int r = v.i + 0x7fffu + ((v.i >> 16) & 1u);  // RNE
  return (unsigned short)(r >> 16);
}

__device__ __forceinline__ uint4 cvt8(const float* __restrict__ p) {
  float4 a = *(const float4*)p;
  float4 b = *(const float4*)(p + 4);
  union { uint4 v; unsigned short u[8]; } d;
  d.u[0] = f2bf(a.x); d.u[1] = f2bf(a.y); d.u[2] = f2bf(a.z); d.u[3] = f2bf(a.w);
  d.u[4] = f2bf(b.x); d.u[5] = f2bf(b.y); d.u[6] = f2bf(b.z); d.u[7] = f2bf(b.w);
  return d.v;
}

// async global->LDS, 16 B/lane; LDS dest = wave-uniform base + lane*16.
__device__ __forceinline__ void gl_lds16(const void* g, void* l) {
  __builtin_amdgcn_global_load_lds(
      (const __attribute__((address_space(1))) void*)g,
      (__attribute__((address_space(3))) void*)l, 16, 0, 0);
}

// ---------------------------------------------------------------------------
// prep: blocks [0,1024)     J transpose -> Bp cols [0,2048)
//       [1024,1088)         I_stim transpose -> Bp cols [2048,2176)
//       [1088,1216)         stim -> Ap cols [2048,2176)   (128 blocks)
//       [1216,1280)         U -> Bp cols [2176,2240)      (64 blocks)
//       [1280,1536)         t split-K partials part[s][b][p] fp32,
//                           FUSED with r -> Ap cols [0,2048) bf16 pack
// ---------------------------------------------------------------------------
__global__ __launch_bounds__(256) void prep(
    const float* __restrict__ J, const float* __restrict__ Ist,
    const float* __restrict__ rg, const float* __restrict__ stim,
    const float* __restrict__ U, const float* __restrict__ V,
    unsigned short* __restrict__ Ap, unsigned short* __restrict__ Bp,
    float* __restrict__ part) {
  __shared__ unsigned short tile[64 * 66];
  __shared__ alignas(16) unsigned short Ats[32 * 64];
  __shared__ alignas(16) unsigned short Bts[64 * 64];
  const int blk = blockIdx.x;
  const int t = threadIdx.x;

  if (blk < 1088) {                      // ---- transposes ----
    const float* src;
    int dst_off, cx, cy;
    if (blk < 1024) { src = J;   dst_off = 0;    cx = blk & 31; cy = blk >> 5; }
    else            { src = Ist; dst_off = 2048; cx = (blk - 1024) & 31; cy = (blk - 1024) >> 5; }
    const int r0 = cy * 64, c0 = cx * 64;
    const int sr = t >> 3, c8 = t & 7;
#pragma unroll
    for (int p = 0; p < 2; ++p) {
      const int row = sr + 32 * p;
      union { uint4 v; unsigned short u[8]; } d;
      d.v = cvt8(&src[(size_t)(r0 + row) * 2048 + c0 + c8 * 8]);
#pragma unroll
      for (int e = 0; e < 8; ++e) tile[row * 66 + c8 * 8 + e] = d.u[e];
    }
    __syncthreads();
#pragma unroll
    for (int p = 0; p < 2; ++p) {
      const int scol = sr + 32 * p;
      union { uint4 v; unsigned short u[8]; } d;
#pragma unroll
      for (int e = 0; e < 8; ++e) d.u[e] = tile[(c8 * 8 + e) * 66 + scol];
      *(uint4*)&Bp[(size_t)(c0 + scol) * KB + dst_off + r0 + c8 * 8] = d.v;
    }
  } else if (blk < 1216) {               // ---- stim -> Ap[2048:2176) ----
    const int row = (blk - 1088) * 16 + (t >> 4);   // 16 rows/block
    const int ch  = t & 15;                         // 16 chunks of 8 floats
    *(uint4*)&Ap[(size_t)row * KA + 2048 + ch * 8] =
        cvt8(&stim[(size_t)row * 128 + ch * 8]);
  } else if (blk < 1280) {               // ---- U -> Bp[2176:2240) ----
    const int row = (blk - 1216) * 32 + (t >> 3);   // 32 rows/block
    const int ch  = t & 7;                          // 8 chunks of 8 floats
    *(uint4*)&Bp[(size_t)row * KB + 2176 + ch * 8] =
        cvt8(&U[(size_t)row * 64 + ch * 8]);
  } else {                               // ---- t split-K partials + r-pack ----
    const int tb = blk - 1280;
    const int mt = tb & 63, s = tb >> 6;
    const int b0 = mt * 32;
    const int wave = t >> 6, lane = t & 63;
    const int q = lane >> 4, l15 = lane & 15;
    const int arow = t >> 3, ac8 = t & 7;

    const float* gA  = rg + (size_t)(b0 + arow) * 2048 + s * 512 + ac8 * 8;
    const float* gB0 = V  + (size_t)arow        * 2048 + s * 512 + ac8 * 8;
    const float* gB1 = V  + (size_t)(arow + 32) * 2048 + s * 512 + ac8 * 8;
    // fused r->Ap pack destination (same elements this block converts)
    unsigned short* pAp = Ap + (size_t)(b0 + arow) * KA + s * 512 + ac8 * 8;

    frag_cd acc0 = {0.f, 0.f, 0.f, 0.f};
    frag_cd acc1 = {0.f, 0.f, 0.f, 0.f};

    for (int kt = 0; kt < 8; ++kt) {
      const int k0 = kt * 64;
      uint4 va  = cvt8(gA + k0);
      uint4 vb0 = cvt8(gB0 + k0);
      uint4 vb1 = cvt8(gB1 + k0);
      *(uint4*)&pAp[k0] = va;          // by-product: Ap bf16 pack
      __syncthreads();
      *(uint4*)&Ats[t * 8]        = va;
      *(uint4*)&Bts[t * 8]        = vb0;
      *(uint4*)&Bts[2048 + t * 8] = vb1;
      __syncthreads();
#pragma unroll
      for (int ks = 0; ks < 2; ++ks) {
        frag_ab a0 = *(const frag_ab*)&Ats[(l15)      * 64 + ks * 32 + q * 8];
        frag_ab a1 = *(const frag_ab*)&Ats[(16 + l15) * 64 + ks * 32 + q * 8];
        frag_ab b  = *(const frag_ab*)&Bts[(wave * 16 + l15) * 64 + ks * 32 + q * 8];
        acc0 = __builtin_amdgcn_mfma_f32_16x16x32_bf16(a0, b, acc0, 0, 0, 0);
        acc1 = __builtin_amdgcn_mfma_f32_16x16x32_bf16(a1, b, acc1, 0, 0, 0);
      }
    }
    const int p = wave * 16 + l15;
#pragma unroll
    for (int reg = 0; reg < 4; ++reg) {
      const int m0 = q * 4 + reg;   // C/D: row = quad*4+reg, col = lane&15
      part[((size_t)s * 2048 + b0 + m0) * 64 + p]      = acc0[reg];
      part[((size_t)s * 2048 + b0 + m0 + 16) * 64 + p] = acc1[reg];
    }
  }
}

// ---------------------------------------------------------------------------
// Pure GEMM + fused t-reduce: 64x64 tile, BK=64, 256 threads (4 waves,
// each 32x32, acc[2][2]). R4's verified dbuf body (counted vmcnt), 34
// K-iters + t/U peel; raw fp32 acc store into accout (measured half-0
// path, 32.6 us profiled in R10). XCD swizzle 16m x 8n. 4 blocks/CU.
// ---------------------------------------------------------------------------
__global__ __launch_bounds__(256, 4) void main_gemm(
    const unsigned short* __restrict__ Ap, const unsigned short* __restrict__ Bp,
    const float* __restrict__ part, const float* __restrict__ tha,
    float* __restrict__ accout) {
  __shared__ alignas(16) unsigned short As[2][64 * 64];   // 2 x 8 KB
  __shared__ alignas(16) unsigned short Bs[2][64 * 64];   // 2 x 8 KB

  const int t = threadIdx.x;
  const int wave = t >> 6, lane = t & 63;
  const int q = lane >> 4, l15 = lane & 15, l7 = lane & 7;
  const int wm = (wave & 1) * 32, wn = (wave >> 1) * 32;

  // XCD swizzle: 1024 blocks, 8 XCDs, each owns 16(m) x 8(n) tiles, n-inner.
  const int bid = blockIdx.x;
  const int xcd = bid & 7, idx = bid >> 3;                 // idx 0..127
  const int mt = ((xcd >> 2) << 4) + (idx >> 3);           // 0..31
  const int nt = ((xcd & 3) << 3) + (idx & 7);             // 0..31
  const int bm0 = mt * 64, bn0 = nt * 64;

  // staging slots: slot ci (16B units) holds row=ci>>3, logical chunk (ci&7)^(row&7)
  const unsigned short* gA[2];
  const unsigned short* gB[2];
  uint4 tval[2];                 // this thread's two t-tile slots (bf16 x8)
#pragma unroll
  for (int r = 0; r < 2; ++r) {
    const int ci = r * 256 + t;
    const int row = ci >> 3;
    const int lc = (ci & 7) ^ (row & 7);
    gA[r] = Ap + (size_t)(bm0 + row) * KA + lc * 8;
    gB[r] = Bp + (size_t)(bn0 + row) * KB + lc * 8;

    // ---- t-tile: t[bm0+row][p0..p0+8) = tha * sum_s part[s] ----
    const int p0 = lc * 8;
    const size_t base = ((size_t)(bm0 + row)) * 64 + p0;
    float4 s0 = *(const float4*)&part[base];
    float4 s1 = *(const float4*)&part[base + 4];
#pragma unroll
    for (int s = 1; s < 4; ++s) {
      float4 a = *(const float4*)&part[(size_t)s * 131072 + base];
      float4 b = *(const float4*)&part[(size_t)s * 131072 + base + 4];
      s0.x += a.x; s0.y += a.y; s0.z += a.z; s0.w += a.w;
      s1.x += b.x; s1.y += b.y; s1.z += b.z; s1.w += b.w;
    }
    float4 th0 = *(const float4*)&tha[base];
    float4 th1 = *(const float4*)&tha[base + 4];
    union { uint4 v; unsigned short u[8]; } d;
    d.u[0] = f2bf(th0.x * s0.x); d.u[1] = f2bf(th0.y * s0.y);
    d.u[2] = f2bf(th0.z * s0.z); d.u[3] = f2bf(th0.w * s0.w);
    d.u[4] = f2bf(th1.x * s1.x); d.u[5] = f2bf(th1.y * s1.y);
    d.u[6] = f2bf(th1.z * s1.z); d.u[7] = f2bf(th1.w * s1.w);
    tval[r] = d.v;
  }

  frag_cd acc[2][2];
#pragma unroll
  for (int i = 0; i < 2; ++i)
#pragma unroll
    for (int j = 0; j < 2; ++j) {
      frag_cd z = {0.f, 0.f, 0.f, 0.f};
      acc[i][j] = z;
    }

  // ---- prologue: drain everything, then stage K-tile 0 into buf 0 ----
  asm volatile("s_waitcnt vmcnt(0)" ::: "memory");
#pragma unroll
  for (int r = 0; r < 2; ++r) {
    gl_lds16(gA[r], &As[0][(size_t)(r * 256 + wave * 64) * 8]);
    gl_lds16(gB[r], &Bs[0][(size_t)(r * 256 + wave * 64) * 8]);
  }

#pragma unroll 1
  for (int kt = 0; kt < 34; ++kt) {  // A' has exactly 34 K-tiles (2176)
    const int cur = kt & 1;
    // barrier 1: all waves done reading buf[cur^1] -> safe to overwrite
    asm volatile("s_waitcnt lgkmcnt(0)" ::: "memory");
    __builtin_amdgcn_s_barrier();
    __builtin_amdgcn_sched_barrier(0);
    if (kt < 33) {
      const int k0n = (kt + 1) * 64;
      unsigned short* dA = &As[cur ^ 1][0];
      unsigned short* dB = &Bs[cur ^ 1][0];
#pragma unroll
      for (int r = 0; r < 2; ++r) {
        gl_lds16(gA[r] + k0n, dA + (size_t)(r * 256 + wave * 64) * 8);
        gl_lds16(gB[r] + k0n, dB + (size_t)(r * 256 + wave * 64) * 8);
      }
      // 8 outstanding; drain exactly tile kt's 4, keep tile kt+1's 4 in flight
      asm volatile("s_waitcnt vmcnt(4)" ::: "memory");
    } else {
      // peeled-tile staging: A-side = t from regs, B-side = U (k0 = 2176)
      unsigned short* dA = &As[cur ^ 1][0];
      unsigned short* dB = &Bs[cur ^ 1][0];
#pragma unroll
      for (int r = 0; r < 2; ++r) {
        *(uint4*)&dA[(size_t)(r * 256 + t) * 8] = tval[r];
        gl_lds16(gB[r] + 34 * 64, dB + (size_t)(r * 256 + wave * 64) * 8);
      }
      // 6 outstanding; drain tile 33's 4, keep the 2 U loads in flight;
      // lgkmcnt(0) drains the tval ds_writes
      asm volatile("s_waitcnt vmcnt(2) lgkmcnt(0)" ::: "memory");
    }
    // barrier 2: buf[cur] fully staged by all waves
    __builtin_amdgcn_s_barrier();
    __builtin_amdgcn_sched_barrier(0);
    const unsigned short* cA = &As[cur][0];
    const unsigned short* cB = &Bs[cur][0];
#pragma unroll
    for (int ks = 0; ks < 2; ++ks) {
      const int lc = ks * 4 + q;
      frag_ab af[2], bfr[2];
#pragma unroll
      for (int i = 0; i < 2; ++i) {
        af[i]  = *(const frag_ab*)&cA[(wm + i * 16 + l15) * 64 + ((lc ^ l7) * 8)];
        bfr[i] = *(const frag_ab*)&cB[(wn + i * 16 + l15) * 64 + ((lc ^ l7) * 8)];
      }
#pragma unroll
      for (int i = 0; i < 2; ++i)
#pragma unroll
        for (int j = 0; j < 2; ++j)
          acc[i][j] = __builtin_amdgcn_mfma_f32_16x16x32_bf16(af[i], bfr[j], acc[i][j], 0, 0, 0);
    }
  }

  // ---- peeled K-tile 34 compute: staged into buf 0 at kt=33 ----
  {
    asm volatile("s_waitcnt vmcnt(0) lgkmcnt(0)" ::: "memory");
    __builtin_amdgcn_s_barrier();
    __builtin_amdgcn_sched_barrier(0);
    const unsigned short* cA = &As[0][0];
    const unsigned short* cB = &Bs[0][0];
#pragma unroll
    for (int ks = 0; ks < 2; ++ks) {
      const int lc = ks * 4 + q;
      frag_ab af[2], bfr[2];
#pragma unroll
      for (int i = 0; i < 2; ++i) {
        af[i]  = *(const frag_ab*)&cA[(wm + i * 16 + l15) * 64 + ((lc ^ l7) * 8)];
        bfr[i] = *(const frag_ab*)&cB[(wn + i * 16 + l15) * 64 + ((lc ^ l7) * 8)];
      }
#pragma unroll
      for (int i = 0; i < 2; ++i)
#pragma unroll
        for (int j = 0; j < 2; ++j)
          acc[i][j] = __builtin_amdgcn_mfma_f32_16x16x32_bf16(af[i], bfr[j], acc[i][j], 0, 0, 0);
    }
  }

  // ---- store raw fp32 accumulator (measured half-0 path) -----------------
#pragma unroll
  for (int j = 0; j < 2; ++j) {
    const int nc = bn0 + wn + j * 16 + l15;        // C/D col = lane&15
#pragma unroll
    for (int i = 0; i < 2; ++i) {
#pragma unroll
      for (int reg = 0; reg < 4; ++reg) {
        const int mr = bm0 + wm + i * 16 + q * 4 + reg;  // C/D row = quad*4+reg
        accout[(size_t)mr * NN + nc] = acc[i][j][reg];
      }
    }
  }
}

// ---------------------------------------------------------------------------
// Streaming epilogue: 1024 blocks x 256 threads x 4 quads (= NQ exactly).
// 4 unrolled stride-262144 passes -> 4 independent coalesced streams per
// thread. Hardware softplus: __logf(1+__expf(x)) (v_log_f32 + v_exp_f32)
// instead of libm log1pf polynomial. outx in-place (acc in, x_new out).
// ---------------------------------------------------------------------------
__global__ __launch_bounds__(256) void epilogue(
    const float* __restrict__ xg, const float* __restrict__ epsg,
    const float* __restrict__ Bvec,
    float* outx /* acc in, x_new out */, float* __restrict__ outr) {
  const float A_DT = 0.33333334f;          // DT/TAU
  const float SIG  = 0.81649658092772615f; // sqrt(2*DT/TAU)
  const int tid = blockIdx.x * 256 + threadIdx.x;   // 0..262143
#pragma unroll
  for (int s = 0; s < 4; ++s) {
    const size_t o = ((size_t)(s * 262144 + tid)) * 4;
    float4 av = *(const float4*)&outx[o];
    float4 xv = *(const float4*)&xg[o];
    float4 ev = *(const float4*)&epsg[o];
    float4 bv = *(const float4*)&Bvec[o & 2047];   // col = o mod 2048

    float4 xn;
    xn.x = xv.x + A_DT * (av.x + bv.x - xv.x + SIG * ev.x);
    xn.y = xv.y + A_DT * (av.y + bv.y - xv.y + SIG * ev.y);
    xn.z = xv.z + A_DT * (av.z + bv.z - xv.z + SIG * ev.z);
    xn.w = xv.w + A_DT * (av.w + bv.w - xv.w + SIG * ev.w);

    float4 rn;
    rn.x = (xn.x > 20.f) ? xn.x : __logf(1.f + __expf(xn.x));
    rn.y = (xn.y > 20.f) ? xn.y : __logf(1.f + __expf(xn.y));
    rn.z = (xn.z > 20.f) ? xn.z : __logf(1.f + __expf(xn.z));
    rn.w = (xn.w > 20.f) ? xn.w : __logf(1.f + __expf(xn.w));

    *(float4*)&outx[o] = xn;
    *(float4*)&outr[o] = rn;
  }
}

// ---------------------------------------------------------------------------
extern "C" void kernel_launch(void* const* d_in, const int* in_sizes, int n_in,
                              void* d_out, int out_size, void* d_ws, size_t ws_size,
                              hipStream_t stream) {
  (void)in_sizes; (void)n_in; (void)out_size; (void)ws_size;
  const float* tha  = (const float*)d_in[0];  // (2048,64)
  const float* stim = (const float*)d_in[1];  // (2048,128)
  const float* x    = (const float*)d_in[2];  // (2048,2048)
  const float* r    = (const float*)d_in[3];  // (2048,2048)
  const float* J    = (const float*)d_in[4];  // (2048,2048)
  const float* Bv   = (const float*)d_in[5];  // (1,2048)
  const float* U    = (const float*)d_in[6];  // (2048,64)
  const float* V    = (const float*)d_in[7];  // (64,2048)
  const float* Ist  = (const float*)d_in[8];  // (128,2048)
  const float* eps  = (const float*)d_in[9];  // (2048,2048)

  unsigned short* Apk = (unsigned short*)d_ws;            // 2048*2176 bf16 (8.5 MB)
  unsigned short* Bpk = Apk + (size_t)NN * KA;            // 2048*2240 bf16 (9.2 MB)
  float* part = (float*)(Bpk + (size_t)NN * KB);          // 4*2048*64 fp32 (2 MB)
  float* outx = (float*)d_out;
  float* outr = outx + (size_t)NN * NN;

  prep<<<1536, 256, 0, stream>>>(J, Ist, r, stim, U, V, Apk, Bpk, part);
  // pure GEMM (+ t/U peel): raw fp32 acc -> outx region
  main_gemm<<<1024, 256, 0, stream>>>(Apk, Bpk, part, tha, outx);
  // streaming epilogue: acc+x+eps -> x_new (in place) + softplus -> outr
  epilogue<<<1024, 256, 0, stream>>>(x, eps, Bv, outx, outr);
}